// Round 11
// baseline (826.866 us; speedup 1.0000x reference)
//
#include <hip/hip_runtime.h>

// ============================================================================
// TemporalPointNet (PointNet++ style) forward on MI355X.
// B=2, T=4 -> BT=8 "batches", N=4096 points, 4 coords (xyz + t).
// SA1: npoint=512, r=0.2, K=32, C_in=4,  MLP 64,64,128
// SA2: npoint=128, r=0.4, K=64, C_in=131, MLP 128,128,256
// SA3: group_all,          K=128, C_in=259, MLP 256,512,1024
//
// R23 == R21 resubmit (R21's bench was lost to infra: "container failed
// twice", no pytest output — same as R16, whose unchanged resubmit R17 ran
// fine). R21 audit: gather bounds all verified in-range; padding values
// bit-identical to the deleted group kernels; LDS 52KB (= R20 passing).
//
// R21 = R20 (817us, best) + gather-in-gemm fusion:
//  - group2_kernel folded into L2_0's A-staging (gmode=2): per-row qb2 gather,
//    cols 0-2 xyz-ctr (__fsub_rn), 3-130 feat1 row, else 0 — bit-identical
//    values; removes a 35.6MB write + 35.6MB read and one dispatch.
//  - group3_kernel folded into L3_0's A-staging (gmode=3) likewise.
//  - Dispatches 17 -> 15. Mode-0 staging path unchanged.
// R20 retained in full:
//  - BN stats via 2x f64 atomicAdd per channel (partS/partQ); consumers
//    derive scale/shift themselves (gemm head LDS table; bn_relu_max inline).
//    No fences (R18: per-block threadfence = per-block L2 writeback, +991us),
//    no complex tails (R19: tail wrecked regalloc, VGPR 72 -> acc spilled).
//  - prep_w piggyback in fps_block; fps_wave piggyback in qb_group1;
//    bn_relu_max+SA2-query_ball fusion.
//  - FPS critical chains byte-identical to R11/R13 measured-best (286us);
//    per-iteration chain is a no-touch zone (R10 +99us, R12 +164us).
// ============================================================================

typedef short s16x8 __attribute__((ext_vector_type(8)));
typedef float f32x4 __attribute__((ext_vector_type(4)));

__device__ __forceinline__ unsigned short f2bf_rne(float f) {
    unsigned u = __float_as_uint(f);
    u += 0x7FFFu + ((u >> 16) & 1u);
    return (unsigned short)(u >> 16);
}
// split f32 -> (hi, lo) bf16 pair: hi = rne(v), lo = rne(v - hi)
__device__ __forceinline__ void f2bf_split(float v, unsigned short& hi,
                                           unsigned short& lo) {
    unsigned u = __float_as_uint(v);
    unsigned r = u + 0x7FFFu + ((u >> 16) & 1u);
    hi = (unsigned short)(r >> 16);
    float vh = __uint_as_float(r & 0xFFFF0000u);
    lo = f2bf_rne(v - vh);
}

__device__ __forceinline__ unsigned long long umax64(unsigned long long a,
                                                     unsigned long long b) {
    return a > b ? a : b;
}

// Wave64 max-reduce via DPP: 1 DPP + 1 max per step (R9 measured-best;
// R10/R12 variants regressed — do not touch).
__device__ __forceinline__ unsigned wred_umax63(unsigned v) {
    unsigned t;
    t = (unsigned)__builtin_amdgcn_update_dpp(0, (int)v, 0x111, 0xf, 0xf, true); if (t > v) v = t;
    t = (unsigned)__builtin_amdgcn_update_dpp(0, (int)v, 0x112, 0xf, 0xf, true); if (t > v) v = t;
    t = (unsigned)__builtin_amdgcn_update_dpp(0, (int)v, 0x114, 0xf, 0xf, true); if (t > v) v = t;
    t = (unsigned)__builtin_amdgcn_update_dpp(0, (int)v, 0x118, 0xf, 0xf, true); if (t > v) v = t;
    t = (unsigned)__builtin_amdgcn_update_dpp(0, (int)v, 0x142, 0xa, 0xf, true); if (t > v) v = t;
    t = (unsigned)__builtin_amdgcn_update_dpp(0, (int)v, 0x143, 0xc, 0xf, true); if (t > v) v = t;
    return v;
}

// Wave argmax of (dist, min-index). Exact first-occurrence argmax.
__device__ __forceinline__ void wave_argmax(unsigned dbits, unsigned nInv,
                                            unsigned& vmax, unsigned& iInv) {
    unsigned m = wred_umax63(dbits);
    vmax = (unsigned)__builtin_amdgcn_readlane((int)m, 63);
    unsigned cand = (dbits == vmax) ? nInv : 0u;
    unsigned im = wred_umax63(cand);
    iInv = (unsigned)__builtin_amdgcn_readlane((int)im, 63);
}

// ---------------- all-layer weight pre-split (device body) ----------------
struct PWArgs {
    const float* w[9];
    unsigned off[9];
    int O[9], C[9], CP[9];
};
__device__ __forceinline__ void prep_w_dev(const PWArgs& a,
                                           unsigned short* __restrict__ wh,
                                           unsigned short* __restrict__ wl,
                                           int i) {
    int l = 0;
#pragma unroll
    for (int k = 1; k < 9; ++k) if (i >= (int)a.off[k]) l = k;
    int li = i - (int)a.off[l];
    int CP = a.CP[l];
    int o = li / CP;
    int c = li - o * CP;
    float v = (c < a.C[l]) ? a.w[l][(size_t)o * a.C[l] + c] : 0.f;
    unsigned short h, lo;
    f2bf_split(v, h, lo);
    wh[i] = h; wl[i] = lo;
}

// ---------------- FPS (multi-wave): one block (NT thr) per batch ------------
// R7/R9 structure (measured best 286us). Blocks >= nFps run the weight
// pre-split (fully hidden in the FPS shadow).
template<int NT, int ITEMS, int STRIDE>
__global__ __launch_bounds__(NT) void fps_block(
    const float* __restrict__ pts, int npoint,
    int* __restrict__ outIdx, float* __restrict__ outXyz,
    int nFps, PWArgs pw, unsigned short* __restrict__ wh,
    unsigned short* __restrict__ wl, int wtotal)
{
    constexpr int N = NT * ITEMS;
    constexpr int NW = NT / 64;
    __shared__ float4 scoord[N];
    __shared__ unsigned long long wkey[2][NW];

    if (blockIdx.x >= nFps) {   // piggyback: weight split on idle CUs
        int i = (blockIdx.x - nFps) * NT + threadIdx.x;
        if (i < wtotal) prep_w_dev(pw, wh, wl, i);
        return;
    }

    const int b = blockIdx.x;
    const int tid = threadIdx.x;
    const int wid = tid >> 6;
    const int lane = tid & 63;
    const float* P = pts + (size_t)b * N * STRIDE;

    float px[ITEMS], py[ITEMS], pz[ITEMS], dloc[ITEMS];
#pragma unroll
    for (int w = 0; w < ITEMS; ++w) {
        int n = tid + w * NT;
        float x, y, z;
        if (STRIDE == 4) {
            float4 v = *(const float4*)(P + (size_t)n * 4);
            x = v.x; y = v.y; z = v.z;
        } else {
            x = P[(size_t)n * STRIDE + 0];
            y = P[(size_t)n * STRIDE + 1];
            z = P[(size_t)n * STRIDE + 2];
        }
        px[w] = x; py[w] = y; pz[w] = z;
        scoord[n] = make_float4(x, y, z, 0.f);
        dloc[w] = 1e10f;
    }
    __syncthreads();
    float4 c0 = scoord[0];
    float cx = c0.x, cy = c0.y, cz = c0.z;
    int far = 0;

    for (int i = 0; i < npoint; ++i) {
        if (tid == 0) {
            outIdx[(size_t)b * npoint + i] = far;
            outXyz[((size_t)b * npoint + i) * 3 + 0] = cx;
            outXyz[((size_t)b * npoint + i) * 3 + 1] = cy;
            outXyz[((size_t)b * npoint + i) * 3 + 2] = cz;
        }
        float bestV = -1.0f;
        int bestW = 0;
#pragma unroll
        for (int w = 0; w < ITEMS; ++w) {
            float dx = __fsub_rn(px[w], cx);
            float dy = __fsub_rn(py[w], cy);
            float dz = __fsub_rn(pz[w], cz);
            float d = __fadd_rn(__fadd_rn(__fmul_rn(dx, dx), __fmul_rn(dy, dy)),
                                __fmul_rn(dz, dz));
            float dd = fminf(dloc[w], d);
            dloc[w] = dd;
            if (dd > bestV) { bestV = dd; bestW = w; }  // strict > : lowest w kept
        }
        int bestN = tid + bestW * NT;   // n grows with w -> min n on tie
        unsigned vmax, iInv;
        wave_argmax(__float_as_uint(bestV), 0xFFFFFFFFu ^ (unsigned)bestN,
                    vmax, iInv);
        const int par = i & 1;
        if (lane == 0)
            wkey[par][wid] = ((unsigned long long)vmax << 32) | iInv;
        __syncthreads();   // single barrier per iteration (parity dbuf)
        unsigned long long kb = wkey[par][0];
#pragma unroll
        for (int w2 = 1; w2 < NW; ++w2) kb = umax64(kb, wkey[par][w2]);
        far = (int)(0xFFFFFFFFu ^ (unsigned)kb);
        float4 cc = scoord[far];   // broadcast, conflict-free
        cx = cc.x; cy = cc.y; cz = cc.z;
    }
}

// ---------------- FPS (single wave, device body, no barriers) ---------------
__device__ void fps_wave_dev(const float* __restrict__ pts, int npoint,
                             int* __restrict__ outIdx, float* __restrict__ outXyz,
                             int b, float4* scoord)
{
    constexpr int ITEMS = 8;
    constexpr int STRIDE = 3;
    constexpr int N = 64 * ITEMS;
    const int tid = threadIdx.x;   // 0..63
    const float* P = pts + (size_t)b * N * STRIDE;

    float px[ITEMS], py[ITEMS], pz[ITEMS], dloc[ITEMS];
#pragma unroll
    for (int w = 0; w < ITEMS; ++w) {
        int n = tid + w * 64;
        float x = P[(size_t)n * STRIDE + 0];
        float y = P[(size_t)n * STRIDE + 1];
        float z = P[(size_t)n * STRIDE + 2];
        px[w] = x; py[w] = y; pz[w] = z;
        scoord[n] = make_float4(x, y, z, 0.f);
        dloc[w] = 1e10f;
    }
    __threadfence_block();
    float4 c0 = scoord[0];
    float cx = c0.x, cy = c0.y, cz = c0.z;
    int far = 0;

    for (int i = 0; i < npoint; ++i) {
        if (tid == 0) {
            outIdx[(size_t)b * npoint + i] = far;
            outXyz[((size_t)b * npoint + i) * 3 + 0] = cx;
            outXyz[((size_t)b * npoint + i) * 3 + 1] = cy;
            outXyz[((size_t)b * npoint + i) * 3 + 2] = cz;
        }
        float bestV = -1.0f;
        int bestW = 0;
#pragma unroll
        for (int w = 0; w < ITEMS; ++w) {
            float dx = __fsub_rn(px[w], cx);
            float dy = __fsub_rn(py[w], cy);
            float dz = __fsub_rn(pz[w], cz);
            float d = __fadd_rn(__fadd_rn(__fmul_rn(dx, dx), __fmul_rn(dy, dy)),
                                __fmul_rn(dz, dz));
            float dd = fminf(dloc[w], d);
            dloc[w] = dd;
            if (dd > bestV) { bestV = dd; bestW = w; }
        }
        int bestN = tid + bestW * 64;
        unsigned vmax, iInv;
        wave_argmax(__float_as_uint(bestV), 0xFFFFFFFFu ^ (unsigned)bestN,
                    vmax, iInv);
        far = (int)(0xFFFFFFFFu ^ iInv);
        float4 cc = scoord[far];
        cx = cc.x; cy = cc.y; cz = cc.z;
    }
}

// ---------------- fused query_ball + group for SA1 (+fps_wave piggyback) ----
__global__ __launch_bounds__(256) void qb_group1(
    const float* __restrict__ xyz /*(8,4096,4)*/,
    const float* __restrict__ ctr /*(8*512,3)*/,
    float* __restrict__ out /*(8*512*32, 8)*/,
    int nQb, const float* __restrict__ fpsPts,
    int* __restrict__ fpsIdx, float* __restrict__ fpsXyz)
{
    __shared__ float4 scoord[512];
    if ((int)blockIdx.x >= nQb) {   // piggyback: single-wave FPS (SA2)
        if (threadIdx.x < 64)
            fps_wave_dev(fpsPts, 128, fpsIdx, fpsXyz,
                         (int)blockIdx.x - nQb, scoord);
        return;
    }
    int gw = (blockIdx.x * 256 + threadIdx.x) >> 6;
    int lane = threadIdx.x & 63;
    if (gw >= 4096) return;
    int b = gw >> 9;
    const float* P = xyz + (size_t)b * 4096 * 4;
    float cx = ctr[(size_t)gw * 3 + 0];
    float cy = ctr[(size_t)gw * 3 + 1];
    float cz = ctr[(size_t)gw * 3 + 2];
    float* out0 = out + (size_t)gw * 32 * 8;
    int cnt = 0;
    float f0x = 0.f, f0y = 0.f, f0z = 0.f, f0t = 0.f;
    bool haveFirst = false;
    for (int base = 0; base < 4096 && cnt < 32; base += 64) {
        int n = base + lane;
        float4 p = *(const float4*)(P + (size_t)n * 4);
        float ex = __fsub_rn(p.x, cx);
        float ey = __fsub_rn(p.y, cy);
        float ez = __fsub_rn(p.z, cz);
        float d = __fadd_rn(__fadd_rn(__fmul_rn(ex, ex), __fmul_rn(ey, ey)),
                            __fmul_rn(ez, ez));
        bool inb = !(d > 0.04f);
        unsigned long long mask = __ballot(inb);
        if (mask) {
            if (!haveFirst) {
                int fl = (int)__builtin_ctzll(mask);   // wave-uniform
                f0x = __shfl(ex, fl); f0y = __shfl(ey, fl);
                f0z = __shfl(ez, fl); f0t = __shfl(p.w, fl);
                haveFirst = true;
            }
            if (inb) {
                int pos = cnt + __builtin_popcountll(mask & ((1ull << lane) - 1ull));
                if (pos < 32) {
                    float* o = out0 + (size_t)pos * 8;
                    *(float4*)o = make_float4(ex, ey, ez, p.w);
                    *(float4*)(o + 4) = make_float4(0.f, 0.f, 0.f, 0.f);
                }
            }
            cnt += (int)__builtin_popcountll(mask);
        }
    }
    if (cnt > 32) cnt = 32;
    for (int p2 = cnt + lane; p2 < 32; p2 += 64) {
        float* o = out0 + (size_t)p2 * 8;
        *(float4*)o = make_float4(f0x, f0y, f0z, f0t);
        *(float4*)(o + 4) = make_float4(0.f, 0.f, 0.f, 0.f);
    }
}

// ---------------- query_ball body (SA2 geometry, device) ----------------
__device__ __forceinline__ void qb2_dev(
    const float* __restrict__ xyz, const float* __restrict__ centers,
    int* __restrict__ outIdx, int gw, int lane)
{
    const int N = 512, stride = 3, S = 128, nsample = 64;
    const float r2 = 0.16f;
    int b = gw / S;
    const float* P = xyz + (size_t)b * N * stride;
    float cx = centers[(size_t)gw * 3 + 0];
    float cy = centers[(size_t)gw * 3 + 1];
    float cz = centers[(size_t)gw * 3 + 2];
    int* out = outIdx + (size_t)gw * nsample;
    int cnt = 0;
    int firstIdx = 0;
    bool haveFirst = false;
    for (int base = 0; base < N && cnt < nsample; base += 64) {
        int n = base + lane;
        bool inb = false;
        if (n < N) {
            float dx = __fsub_rn(cx, P[(size_t)n * stride + 0]);
            float dy = __fsub_rn(cy, P[(size_t)n * stride + 1]);
            float dz = __fsub_rn(cz, P[(size_t)n * stride + 2]);
            float d = __fadd_rn(__fadd_rn(__fmul_rn(dx, dx), __fmul_rn(dy, dy)),
                                __fmul_rn(dz, dz));
            inb = !(d > r2);
        }
        unsigned long long mask = __ballot(inb);
        if (mask) {
            if (!haveFirst) { firstIdx = base + __builtin_ctzll(mask); haveFirst = true; }
            if (inb) {
                int pos = cnt + __builtin_popcountll(mask & ((1ull << lane) - 1ull));
                if (pos < nsample) out[pos] = n;
            }
            cnt += (int)__builtin_popcountll(mask);
        }
    }
    if (cnt > nsample) cnt = nsample;
    for (int p = cnt + lane; p < nsample; p += 64) out[p] = firstIdx;
}

// ---------------- fused GEMM: Y = act/gather(X) * W^T + BN stat-sums -------
// R20 body with a gather-mode A-staging:
//  gmode 0: X rows direct (float4; applyAct BN from derived sScale/sShift).
//  gmode 2: group2 inline — row sk: qb2 gather; c<3 xyz-ctr; c<131 feat1.
//  gmode 3: group3 inline — row sk: c<3 nx2; c<259 feat2.
// Tail: per-channel block sums via 2x atomicAdd(double) into partS/partQ.
__global__ __launch_bounds__(256) void gemm_fused(
    const float* __restrict__ X,
    const double* __restrict__ pSin, const double* __restrict__ pQin,
    const float* __restrict__ gIn, const float* __restrict__ bIn,
    double invMin, int applyAct,
    const unsigned short* __restrict__ Bh, const unsigned short* __restrict__ Bl,
    float* __restrict__ Y,
    double* __restrict__ pSout, double* __restrict__ pQout,
    int AC, int CPW, int O, int gmode,
    const int* __restrict__ gqb, const float* __restrict__ gxyz,
    const float* __restrict__ gctr, const float* __restrict__ gfeat)
{
    constexpr int PITCH = 40;
    __shared__ __align__(16) unsigned short sAh[128 * PITCH];
    __shared__ __align__(16) unsigned short sAl[128 * PITCH];
    __shared__ __align__(16) unsigned short sBh[128 * PITCH];
    __shared__ __align__(16) unsigned short sBl[128 * PITCH];
    __shared__ float sred[2048];
    __shared__ float sScale[512];
    __shared__ float sShift[512];

    const int tid = threadIdx.x;
    const int lane = tid & 63;
    const int wid = tid >> 6;
    const int col15 = lane & 15;
    const int quad = lane >> 4;
    const int wm = (wid >> 1) * 64;
    const int wo = (wid & 1) * 64;
    const int m0 = blockIdx.x * 128;
    const int o0 = blockIdx.y * 128;
    const int lr = tid >> 2;
    const int lc = (tid & 3) * 8;

    // head: derive this layer's input BN scale/shift from summed stats.
    if (applyAct) {
        for (int c = tid; c < AC; c += 256) {
            double S = pSin[c], Q = pQin[c];
            double mean = S * invMin;
            double var = Q * invMin - mean * mean;
            float varf = (float)var;
            if (varf < 0.f) varf = 0.f;
            float sc = gIn[c] * rsqrtf(varf + 1e-5f);
            sScale[c] = sc;
            sShift[c] = bIn[c] - (float)mean * sc;
        }
    }
    __syncthreads();

    f32x4 acc[4][4];
#pragma unroll
    for (int mt = 0; mt < 4; ++mt)
#pragma unroll
        for (int ot = 0; ot < 4; ++ot)
            acc[mt][ot] = {0.f, 0.f, 0.f, 0.f};

    for (int k0 = 0; k0 < CPW; k0 += 32) {
#pragma unroll
        for (int it = 0; it < 2; ++it) {
            int r = lr + it * 64;
            int c = k0 + lc;
            unsigned short h[8], l[8];
            float vv[8];
            bool have = true;
            if (gmode == 0) {
                if (c + 8 <= AC) {
                    const float* xr = X + (size_t)(m0 + r) * AC + c;
                    float4 v0 = *(const float4*)xr;
                    float4 v1 = *(const float4*)(xr + 4);
                    vv[0] = v0.x; vv[1] = v0.y; vv[2] = v0.z; vv[3] = v0.w;
                    vv[4] = v1.x; vv[5] = v1.y; vv[6] = v1.z; vv[7] = v1.w;
                    if (applyAct) {
#pragma unroll
                        for (int j = 0; j < 8; ++j)
                            vv[j] = fmaxf(vv[j] * sScale[c + j] + sShift[c + j], 0.f);
                    }
                } else {
                    have = false;
                }
            } else if (gmode == 2) {
                // group2 inline: row m = sk in (8,128,64) flattened
                int m = m0 + r;
                int idx = gqb[m];
                idx = (idx < 0) ? 0 : (idx > 511 ? 511 : idx);
                int bb2 = m >> 13;          // / (128*64)
                int bs = m >> 6;            // / 64
                const float* frow = gfeat + ((size_t)bb2 * 512 + idx) * 128;
                const float* xrow = gxyz + ((size_t)bb2 * 512 + idx) * 3;
                const float* crow = gctr + (size_t)bs * 3;
#pragma unroll
                for (int j = 0; j < 8; ++j) {
                    int cc = c + j;
                    float v = 0.f;
                    if (cc < 3)        v = __fsub_rn(xrow[cc], crow[cc]);
                    else if (cc < 131) v = frow[cc - 3];
                    vv[j] = v;
                }
            } else {
                // group3 inline: row m = sk in (8*128) == 1024 rows
                int m = m0 + r;
                const float* frow = gfeat + (size_t)m * 256;
                const float* crow = gctr + (size_t)m * 3;
#pragma unroll
                for (int j = 0; j < 8; ++j) {
                    int cc = c + j;
                    float v = 0.f;
                    if (cc < 3)        v = crow[cc];
                    else if (cc < 259) v = frow[cc - 3];
                    vv[j] = v;
                }
            }
            if (have) {
#pragma unroll
                for (int j = 0; j < 8; ++j) f2bf_split(vv[j], h[j], l[j]);
            } else {
#pragma unroll
                for (int j = 0; j < 8; ++j) { h[j] = 0; l[j] = 0; }
            }
            *(ushort4*)&sAh[r * PITCH + lc] = make_ushort4(h[0], h[1], h[2], h[3]);
            *(ushort4*)&sAh[r * PITCH + lc + 4] = make_ushort4(h[4], h[5], h[6], h[7]);
            *(ushort4*)&sAl[r * PITCH + lc] = make_ushort4(l[0], l[1], l[2], l[3]);
            *(ushort4*)&sAl[r * PITCH + lc + 4] = make_ushort4(l[4], l[5], l[6], l[7]);
        }
#pragma unroll
        for (int it = 0; it < 2; ++it) {
            int r = lr + it * 64;
            int c = k0 + lc;
            int o = o0 + r;
            uint4 vh = {0, 0, 0, 0}, vl = {0, 0, 0, 0};
            if (o < O && c < CPW) {
                size_t goff = (size_t)o * CPW + c;
                vh = *(const uint4*)(Bh + goff);
                vl = *(const uint4*)(Bl + goff);
            }
            *(uint4*)&sBh[r * PITCH + lc] = vh;
            *(uint4*)&sBl[r * PITCH + lc] = vl;
        }
        __syncthreads();
        s16x8 ah[4], al[4], bh[4], bl[4];
#pragma unroll
        for (int mt = 0; mt < 4; ++mt) {
            int rowoff = (wm + mt * 16 + col15) * PITCH + quad * 8;
            ah[mt] = *(const s16x8*)&sAh[rowoff];
            al[mt] = *(const s16x8*)&sAl[rowoff];
        }
#pragma unroll
        for (int ot = 0; ot < 4; ++ot) {
            int rowoff = (wo + ot * 16 + col15) * PITCH + quad * 8;
            bh[ot] = *(const s16x8*)&sBh[rowoff];
            bl[ot] = *(const s16x8*)&sBl[rowoff];
        }
#pragma unroll
        for (int mt = 0; mt < 4; ++mt)
#pragma unroll
            for (int ot = 0; ot < 4; ++ot) {
                acc[mt][ot] = __builtin_amdgcn_mfma_f32_16x16x32_bf16(
                    ah[mt], bl[ot], acc[mt][ot], 0, 0, 0);
                acc[mt][ot] = __builtin_amdgcn_mfma_f32_16x16x32_bf16(
                    al[mt], bh[ot], acc[mt][ot], 0, 0, 0);
                acc[mt][ot] = __builtin_amdgcn_mfma_f32_16x16x32_bf16(
                    ah[mt], bh[ot], acc[mt][ot], 0, 0, 0);
            }
        __syncthreads();
    }
#pragma unroll
    for (int mt = 0; mt < 4; ++mt)
#pragma unroll
        for (int ot = 0; ot < 4; ++ot) {
            int og = o0 + wo + ot * 16 + col15;
            if (og < O) {
#pragma unroll
                for (int r = 0; r < 4; ++r) {
                    int mg = m0 + wm + mt * 16 + quad * 4 + r;
                    Y[(size_t)mg * O + og] = acc[mt][ot][r];
                }
            }
        }
    // BN stats epilogue (R13-identical fixed-order block combine), then two
    // f64 atomicAdds per channel (simple tail — no register-pressure bomb).
#pragma unroll
    for (int ot = 0; ot < 4; ++ot) {
        float s = 0.f, s2 = 0.f;
#pragma unroll
        for (int mt = 0; mt < 4; ++mt)
#pragma unroll
            for (int r = 0; r < 4; ++r) {
                float v = acc[mt][ot][r];
                s += v;
                s2 += v * v;
            }
        int slot = ((wid * 4 + quad) * 16 + col15) * 4 + ot;
        sred[slot * 2] = s;
        sred[slot * 2 + 1] = s2;
    }
    __syncthreads();
    if (tid < 128) {
        int col = tid;
        int o = o0 + col;
        if (o < O) {
            int cb = col >> 6;
            int ot = (col & 63) >> 4;
            int c15 = col & 15;
            double S = 0.0, S2 = 0.0;
#pragma unroll
            for (int wp = 0; wp < 2; ++wp) {
                int wd = cb + wp * 2;
#pragma unroll
                for (int q = 0; q < 4; ++q) {
                    int slot = ((wd * 4 + q) * 16 + c15) * 4 + ot;
                    S += (double)sred[slot * 2];
                    S2 += (double)sred[slot * 2 + 1];
                }
            }
            atomicAdd(&pSout[o], S);
            atomicAdd(&pQout[o], S2);
        }
    }
}

// ---------------- BN + ReLU + max over K (+ optional SA2 query_ball) -------
// Computes its channel's scale/shift inline from the summed stats (identical
// formula/inputs in every block -> identical values; no finalize dispatch).
__global__ __launch_bounds__(256) void bn_relu_max(
    const float* __restrict__ Y,
    const double* __restrict__ pS, const double* __restrict__ pQ,
    const float* __restrict__ gv, const float* __restrict__ bv, double invM,
    float* __restrict__ out, int Stot, int K, int O, int nMain,
    const float* __restrict__ qbXyz, const float* __restrict__ qbCtr,
    int* __restrict__ qbOut)
{
    if ((int)blockIdx.x >= nMain) {   // piggyback: SA2 query_ball (4 waves)
        int wid = threadIdx.x >> 6, lane = threadIdx.x & 63;
        int gw = ((int)blockIdx.x - nMain) * 4 + wid;
        if (gw < 1024) qb2_dev(qbXyz, qbCtr, qbOut, gw, lane);
        return;
    }
    int idx = blockIdx.x * 256 + threadIdx.x;
    if (idx >= Stot * O) return;
    int s = idx / O;
    int o = idx - s * O;
    double S = pS[o], Q = pQ[o];
    double mean = S * invM;
    double var = Q * invM - mean * mean;
    float varf = (float)var;
    if (varf < 0.f) varf = 0.f;
    float sc = gv[o] * rsqrtf(varf + 1e-5f);
    float sh = bv[o] - (float)mean * sc;
    const float* basep = Y + (size_t)s * K * O + o;
    float mx = 0.f;
    for (int k = 0; k < K; ++k) {
        float v = basep[(size_t)k * O] * sc + sh;
        v = fmaxf(v, 0.f);
        mx = fmaxf(mx, v);
    }
    out[idx] = mx;
}

// ============================================================================
extern "C" void kernel_launch(void* const* d_in, const int* in_sizes, int n_in,
                              void* d_out, int out_size, void* d_ws, size_t ws_size,
                              hipStream_t stream)
{
    const float* xin = (const float*)d_in[0];
    const float* w[9]; const float* g[9]; const float* bb[9];
    for (int i = 0; i < 9; ++i) {
        w[i]  = (const float*)d_in[1 + 3 * i];
        g[i]  = (const float*)d_in[2 + 3 * i];
        bb[i] = (const float*)d_in[3 + 3 * i];
    }

    char* base = (char*)d_ws;
    size_t off = 0;
    auto alloc = [&](size_t bytes) -> void* {
        void* p = base + off;
        off = (off + bytes + 255) & ~(size_t)255;
        return p;
    };
    const int OC[9][3] = {{64,4,8},{64,64,64},{128,64,64},
                          {128,131,136},{128,128,128},{256,128,128},
                          {256,259,264},{512,256,256},{1024,512,512}};
    size_t woff[10]; woff[0] = 0;
    for (int i = 0; i < 9; ++i) woff[i + 1] = woff[i] + (size_t)OC[i][0] * OC[i][2];

    // --- small / metadata region (memset-protected) ---
    int*    fps1   = (int*)alloc((size_t)4096 * 4);
    int*    fps2   = (int*)alloc((size_t)1024 * 4);
    int*    qb2    = (int*)alloc((size_t)65536 * 4);
    float*  nx1    = (float*)alloc((size_t)12288 * 4);
    float*  nx2    = (float*)alloc((size_t)3072 * 4);
    float*  feat1  = (float*)alloc((size_t)524288 * 4);
    float*  feat2  = (float*)alloc((size_t)262144 * 4);
    double* partS  = (double*)alloc((size_t)9 * 1024 * 8);   // per-layer sums
    double* partQ  = (double*)alloc((size_t)9 * 1024 * 8);   // per-layer sumsq
    unsigned short* WH = (unsigned short*)alloc(woff[9] * 2);
    unsigned short* WL = (unsigned short*)alloc(woff[9] * 2);
    const size_t zeroBytes = off;
    // --- big ping/pong buffers (fully written before read at every use) ---
    float*  XG = (float*)alloc((size_t)65536 * 136 * 4);
    float*  A  = (float*)alloc((size_t)16777216 * 4);
    if (off > ws_size) return;

    // Defensive zero of the metadata region only (~5 MB): indices and the
    // per-layer stat accumulators start at 0 every invocation.
    hipMemsetAsync(d_ws, 0, zeroBytes, stream);

    PWArgs pwa;
    for (int i = 0; i < 9; ++i) {
        pwa.w[i] = w[i]; pwa.off[i] = (unsigned)woff[i];
        pwa.O[i] = OC[i][0]; pwa.C[i] = OC[i][1]; pwa.CP[i] = OC[i][2];
    }
    const int nPrep = (int)((woff[9] + 255) / 256);

    auto gemm = [&](const float* X, int prevLi, double invMprev, int li,
                    float* Y, int YB, int OB, int AC, int CPW, int O,
                    int gmode, const int* gqb, const float* gxyz,
                    const float* gctr, const float* gfeat) {
        gemm_fused<<<dim3(YB, OB), 256, 0, stream>>>(
            X,
            prevLi >= 0 ? partS + (size_t)prevLi * 1024 : nullptr,
            prevLi >= 0 ? partQ + (size_t)prevLi * 1024 : nullptr,
            prevLi >= 0 ? g[prevLi] : nullptr,
            prevLi >= 0 ? bb[prevLi] : nullptr,
            invMprev, prevLi >= 0 ? 1 : 0,
            WH + woff[li], WL + woff[li], Y,
            partS + (size_t)li * 1024, partQ + (size_t)li * 1024,
            AC, CPW, O, gmode, gqb, gxyz, gctr, gfeat);
    };

    const double inv1 = 1.0 / 131072.0;
    const double inv2 = 1.0 / 65536.0;
    const double inv3 = 1.0 / 1024.0;

    // ---------------- SA1 ----------------
    fps_block<256, 16, 4><<<8 + nPrep, 256, 0, stream>>>(
        xin, 512, fps1, nx1, 8, pwa, WH, WL, (int)woff[9]);
    // qb_group1 blocks 0-1023: group; 1024-1031: SA2 single-wave FPS.
    qb_group1<<<1024 + 8, 256, 0, stream>>>(xin, nx1, XG, 1024, nx1, fps2, nx2);

    gemm(XG, -1, 0.0, 0, A, 1024, 1, 8, 8, 64, 0, nullptr, nullptr, nullptr, nullptr);
    gemm(A, 0, inv1, 1, XG, 1024, 1, 64, 64, 64, 0, nullptr, nullptr, nullptr, nullptr);
    gemm(XG, 1, inv1, 2, A, 1024, 1, 64, 64, 128, 0, nullptr, nullptr, nullptr, nullptr);
    // bn_relu_max (2048 blocks) + SA2 query_ball (256 blocks) fused.
    bn_relu_max<<<2048 + 256, 256, 0, stream>>>(
        A, partS + 2 * 1024, partQ + 2 * 1024, g[2], bb[2], inv1,
        feat1, 4096, 32, 128, 2048, nx1, nx2, qb2);

    // ---------------- SA2 ----------------
    // L2_0: A-staging gathers group2 inline (qb2/nx1/feat1) — no XG pass.
    gemm(nullptr, -1, 0.0, 3, A, 512, 1, 136, 136, 128, 2, qb2, nx1, nx2, feat1);
    gemm(A, 3, inv2, 4, XG, 512, 1, 128, 128, 128, 0, nullptr, nullptr, nullptr, nullptr);
    gemm(XG, 4, inv2, 5, A, 512, 2, 128, 128, 256, 0, nullptr, nullptr, nullptr, nullptr);
    bn_relu_max<<<(1024 * 256) / 256, 256, 0, stream>>>(
        A, partS + 5 * 1024, partQ + 5 * 1024, g[5], bb[5], inv2,
        feat2, 1024, 64, 256, 1024 * 256 / 256, nullptr, nullptr, nullptr);

    // ---------------- SA3 (group_all) ----------------
    // L3_0: A-staging gathers group3 inline (nx2/feat2) — no XG pass.
    gemm(nullptr, -1, 0.0, 6, A, 8, 2, 264, 264, 256, 3, nullptr, nullptr, nx2, feat2);
    gemm(A, 6, inv3, 7, XG, 8, 4, 256, 256, 512, 0, nullptr, nullptr, nullptr, nullptr);
    gemm(XG, 7, inv3, 8, A, 8, 8, 512, 512, 1024, 0, nullptr, nullptr, nullptr, nullptr);
    bn_relu_max<<<(8 * 1024) / 256, 256, 0, stream>>>(
        A, partS + 8 * 1024, partQ + 8 * 1024, g[8], bb[8], inv3,
        (float*)d_out, 8, 128, 1024, (8 * 1024) / 256,
        nullptr, nullptr, nullptr);
}

// Round 12
// 794.833 us; speedup vs baseline: 1.0403x; 1.0403x over previous
//
#include <hip/hip_runtime.h>

// ============================================================================
// TemporalPointNet (PointNet++ style) forward on MI355X.
// B=2, T=4 -> BT=8 "batches", N=4096 points, 4 coords (xyz + t).
// SA1: npoint=512, r=0.2, K=32, C_in=4,  MLP 64,64,128
// SA2: npoint=128, r=0.4, K=64, C_in=131, MLP 128,128,256
// SA3: group_all,          K=128, C_in=259, MLP 256,512,1024
//
// R24 = R23 (827us ~ R20's 817, within noise) + in-gemm K-reduction for the
// .2 layers:
//  - L1_2 (K=32) / L2_2 (K=64): each 128-row tile holds whole centers (4/2).
//    relu(v*sc+sh) is monotone in v (sc>=0) / antitone (sc<0), so
//    max_k relu(v_k*sc+sh) == relu(vsel*sc+sh), vsel = sc>=0 ? max_k v
//    : min_k v — EXACT. gemm epilogue (redK mode) skips the Y store and
//    writes per-(center,channel) Vmax/Vmin instead (fmax/fmin + 2 shfl_xor
//    over quads; writers disjoint). Saves 67MB write + 67MB read per layer.
//  - bn_relu_max vmode=1: 2 loads + select instead of a K-row loop.
//  - L3_2 (4MB) keeps the plain path. Stats epilogue unchanged. Tail stays
//    lean (R19 lesson: no register-pressure bombs).
// R23/R21/R20 retained: gather-in-gemm (gmode 2/3) for L2_0/L3_0; BN stats
// via 2x f64 atomicAdd + consumer-side scale/shift (no fences — R18; no
// complex tails — R19); prep_w piggyback in fps_block; fps_wave piggyback
// in qb_group1; bn_relu_max+SA2-query_ball fusion. FPS chains byte-identical
// to R11/R13 measured-best (286us); per-iteration chain is a no-touch zone.
// ============================================================================

typedef short s16x8 __attribute__((ext_vector_type(8)));
typedef float f32x4 __attribute__((ext_vector_type(4)));

__device__ __forceinline__ unsigned short f2bf_rne(float f) {
    unsigned u = __float_as_uint(f);
    u += 0x7FFFu + ((u >> 16) & 1u);
    return (unsigned short)(u >> 16);
}
// split f32 -> (hi, lo) bf16 pair: hi = rne(v), lo = rne(v - hi)
__device__ __forceinline__ void f2bf_split(float v, unsigned short& hi,
                                           unsigned short& lo) {
    unsigned u = __float_as_uint(v);
    unsigned r = u + 0x7FFFu + ((u >> 16) & 1u);
    hi = (unsigned short)(r >> 16);
    float vh = __uint_as_float(r & 0xFFFF0000u);
    lo = f2bf_rne(v - vh);
}

__device__ __forceinline__ unsigned long long umax64(unsigned long long a,
                                                     unsigned long long b) {
    return a > b ? a : b;
}

// Wave64 max-reduce via DPP: 1 DPP + 1 max per step (R9 measured-best;
// R10/R12 variants regressed — do not touch).
__device__ __forceinline__ unsigned wred_umax63(unsigned v) {
    unsigned t;
    t = (unsigned)__builtin_amdgcn_update_dpp(0, (int)v, 0x111, 0xf, 0xf, true); if (t > v) v = t;
    t = (unsigned)__builtin_amdgcn_update_dpp(0, (int)v, 0x112, 0xf, 0xf, true); if (t > v) v = t;
    t = (unsigned)__builtin_amdgcn_update_dpp(0, (int)v, 0x114, 0xf, 0xf, true); if (t > v) v = t;
    t = (unsigned)__builtin_amdgcn_update_dpp(0, (int)v, 0x118, 0xf, 0xf, true); if (t > v) v = t;
    t = (unsigned)__builtin_amdgcn_update_dpp(0, (int)v, 0x142, 0xa, 0xf, true); if (t > v) v = t;
    t = (unsigned)__builtin_amdgcn_update_dpp(0, (int)v, 0x143, 0xc, 0xf, true); if (t > v) v = t;
    return v;
}

// Wave argmax of (dist, min-index). Exact first-occurrence argmax.
__device__ __forceinline__ void wave_argmax(unsigned dbits, unsigned nInv,
                                            unsigned& vmax, unsigned& iInv) {
    unsigned m = wred_umax63(dbits);
    vmax = (unsigned)__builtin_amdgcn_readlane((int)m, 63);
    unsigned cand = (dbits == vmax) ? nInv : 0u;
    unsigned im = wred_umax63(cand);
    iInv = (unsigned)__builtin_amdgcn_readlane((int)im, 63);
}

// ---------------- all-layer weight pre-split (device body) ----------------
struct PWArgs {
    const float* w[9];
    unsigned off[9];
    int O[9], C[9], CP[9];
};
__device__ __forceinline__ void prep_w_dev(const PWArgs& a,
                                           unsigned short* __restrict__ wh,
                                           unsigned short* __restrict__ wl,
                                           int i) {
    int l = 0;
#pragma unroll
    for (int k = 1; k < 9; ++k) if (i >= (int)a.off[k]) l = k;
    int li = i - (int)a.off[l];
    int CP = a.CP[l];
    int o = li / CP;
    int c = li - o * CP;
    float v = (c < a.C[l]) ? a.w[l][(size_t)o * a.C[l] + c] : 0.f;
    unsigned short h, lo;
    f2bf_split(v, h, lo);
    wh[i] = h; wl[i] = lo;
}

// ---------------- FPS (multi-wave): one block (NT thr) per batch ------------
// R7/R9 structure (measured best 286us). Blocks >= nFps run the weight
// pre-split (fully hidden in the FPS shadow).
template<int NT, int ITEMS, int STRIDE>
__global__ __launch_bounds__(NT) void fps_block(
    const float* __restrict__ pts, int npoint,
    int* __restrict__ outIdx, float* __restrict__ outXyz,
    int nFps, PWArgs pw, unsigned short* __restrict__ wh,
    unsigned short* __restrict__ wl, int wtotal)
{
    constexpr int N = NT * ITEMS;
    constexpr int NW = NT / 64;
    __shared__ float4 scoord[N];
    __shared__ unsigned long long wkey[2][NW];

    if (blockIdx.x >= nFps) {   // piggyback: weight split on idle CUs
        int i = (blockIdx.x - nFps) * NT + threadIdx.x;
        if (i < wtotal) prep_w_dev(pw, wh, wl, i);
        return;
    }

    const int b = blockIdx.x;
    const int tid = threadIdx.x;
    const int wid = tid >> 6;
    const int lane = tid & 63;
    const float* P = pts + (size_t)b * N * STRIDE;

    float px[ITEMS], py[ITEMS], pz[ITEMS], dloc[ITEMS];
#pragma unroll
    for (int w = 0; w < ITEMS; ++w) {
        int n = tid + w * NT;
        float x, y, z;
        if (STRIDE == 4) {
            float4 v = *(const float4*)(P + (size_t)n * 4);
            x = v.x; y = v.y; z = v.z;
        } else {
            x = P[(size_t)n * STRIDE + 0];
            y = P[(size_t)n * STRIDE + 1];
            z = P[(size_t)n * STRIDE + 2];
        }
        px[w] = x; py[w] = y; pz[w] = z;
        scoord[n] = make_float4(x, y, z, 0.f);
        dloc[w] = 1e10f;
    }
    __syncthreads();
    float4 c0 = scoord[0];
    float cx = c0.x, cy = c0.y, cz = c0.z;
    int far = 0;

    for (int i = 0; i < npoint; ++i) {
        if (tid == 0) {
            outIdx[(size_t)b * npoint + i] = far;
            outXyz[((size_t)b * npoint + i) * 3 + 0] = cx;
            outXyz[((size_t)b * npoint + i) * 3 + 1] = cy;
            outXyz[((size_t)b * npoint + i) * 3 + 2] = cz;
        }
        float bestV = -1.0f;
        int bestW = 0;
#pragma unroll
        for (int w = 0; w < ITEMS; ++w) {
            float dx = __fsub_rn(px[w], cx);
            float dy = __fsub_rn(py[w], cy);
            float dz = __fsub_rn(pz[w], cz);
            float d = __fadd_rn(__fadd_rn(__fmul_rn(dx, dx), __fmul_rn(dy, dy)),
                                __fmul_rn(dz, dz));
            float dd = fminf(dloc[w], d);
            dloc[w] = dd;
            if (dd > bestV) { bestV = dd; bestW = w; }  // strict > : lowest w kept
        }
        int bestN = tid + bestW * NT;   // n grows with w -> min n on tie
        unsigned vmax, iInv;
        wave_argmax(__float_as_uint(bestV), 0xFFFFFFFFu ^ (unsigned)bestN,
                    vmax, iInv);
        const int par = i & 1;
        if (lane == 0)
            wkey[par][wid] = ((unsigned long long)vmax << 32) | iInv;
        __syncthreads();   // single barrier per iteration (parity dbuf)
        unsigned long long kb = wkey[par][0];
#pragma unroll
        for (int w2 = 1; w2 < NW; ++w2) kb = umax64(kb, wkey[par][w2]);
        far = (int)(0xFFFFFFFFu ^ (unsigned)kb);
        float4 cc = scoord[far];   // broadcast, conflict-free
        cx = cc.x; cy = cc.y; cz = cc.z;
    }
}

// ---------------- FPS (single wave, device body, no barriers) ---------------
__device__ void fps_wave_dev(const float* __restrict__ pts, int npoint,
                             int* __restrict__ outIdx, float* __restrict__ outXyz,
                             int b, float4* scoord)
{
    constexpr int ITEMS = 8;
    constexpr int STRIDE = 3;
    constexpr int N = 64 * ITEMS;
    const int tid = threadIdx.x;   // 0..63
    const float* P = pts + (size_t)b * N * STRIDE;

    float px[ITEMS], py[ITEMS], pz[ITEMS], dloc[ITEMS];
#pragma unroll
    for (int w = 0; w < ITEMS; ++w) {
        int n = tid + w * 64;
        float x = P[(size_t)n * STRIDE + 0];
        float y = P[(size_t)n * STRIDE + 1];
        float z = P[(size_t)n * STRIDE + 2];
        px[w] = x; py[w] = y; pz[w] = z;
        scoord[n] = make_float4(x, y, z, 0.f);
        dloc[w] = 1e10f;
    }
    __threadfence_block();
    float4 c0 = scoord[0];
    float cx = c0.x, cy = c0.y, cz = c0.z;
    int far = 0;

    for (int i = 0; i < npoint; ++i) {
        if (tid == 0) {
            outIdx[(size_t)b * npoint + i] = far;
            outXyz[((size_t)b * npoint + i) * 3 + 0] = cx;
            outXyz[((size_t)b * npoint + i) * 3 + 1] = cy;
            outXyz[((size_t)b * npoint + i) * 3 + 2] = cz;
        }
        float bestV = -1.0f;
        int bestW = 0;
#pragma unroll
        for (int w = 0; w < ITEMS; ++w) {
            float dx = __fsub_rn(px[w], cx);
            float dy = __fsub_rn(py[w], cy);
            float dz = __fsub_rn(pz[w], cz);
            float d = __fadd_rn(__fadd_rn(__fmul_rn(dx, dx), __fmul_rn(dy, dy)),
                                __fmul_rn(dz, dz));
            float dd = fminf(dloc[w], d);
            dloc[w] = dd;
            if (dd > bestV) { bestV = dd; bestW = w; }
        }
        int bestN = tid + bestW * 64;
        unsigned vmax, iInv;
        wave_argmax(__float_as_uint(bestV), 0xFFFFFFFFu ^ (unsigned)bestN,
                    vmax, iInv);
        far = (int)(0xFFFFFFFFu ^ iInv);
        float4 cc = scoord[far];
        cx = cc.x; cy = cc.y; cz = cc.z;
    }
}

// ---------------- fused query_ball + group for SA1 (+fps_wave piggyback) ----
__global__ __launch_bounds__(256) void qb_group1(
    const float* __restrict__ xyz /*(8,4096,4)*/,
    const float* __restrict__ ctr /*(8*512,3)*/,
    float* __restrict__ out /*(8*512*32, 8)*/,
    int nQb, const float* __restrict__ fpsPts,
    int* __restrict__ fpsIdx, float* __restrict__ fpsXyz)
{
    __shared__ float4 scoord[512];
    if ((int)blockIdx.x >= nQb) {   // piggyback: single-wave FPS (SA2)
        if (threadIdx.x < 64)
            fps_wave_dev(fpsPts, 128, fpsIdx, fpsXyz,
                         (int)blockIdx.x - nQb, scoord);
        return;
    }
    int gw = (blockIdx.x * 256 + threadIdx.x) >> 6;
    int lane = threadIdx.x & 63;
    if (gw >= 4096) return;
    int b = gw >> 9;
    const float* P = xyz + (size_t)b * 4096 * 4;
    float cx = ctr[(size_t)gw * 3 + 0];
    float cy = ctr[(size_t)gw * 3 + 1];
    float cz = ctr[(size_t)gw * 3 + 2];
    float* out0 = out + (size_t)gw * 32 * 8;
    int cnt = 0;
    float f0x = 0.f, f0y = 0.f, f0z = 0.f, f0t = 0.f;
    bool haveFirst = false;
    for (int base = 0; base < 4096 && cnt < 32; base += 64) {
        int n = base + lane;
        float4 p = *(const float4*)(P + (size_t)n * 4);
        float ex = __fsub_rn(p.x, cx);
        float ey = __fsub_rn(p.y, cy);
        float ez = __fsub_rn(p.z, cz);
        float d = __fadd_rn(__fadd_rn(__fmul_rn(ex, ex), __fmul_rn(ey, ey)),
                            __fmul_rn(ez, ez));
        bool inb = !(d > 0.04f);
        unsigned long long mask = __ballot(inb);
        if (mask) {
            if (!haveFirst) {
                int fl = (int)__builtin_ctzll(mask);   // wave-uniform
                f0x = __shfl(ex, fl); f0y = __shfl(ey, fl);
                f0z = __shfl(ez, fl); f0t = __shfl(p.w, fl);
                haveFirst = true;
            }
            if (inb) {
                int pos = cnt + __builtin_popcountll(mask & ((1ull << lane) - 1ull));
                if (pos < 32) {
                    float* o = out0 + (size_t)pos * 8;
                    *(float4*)o = make_float4(ex, ey, ez, p.w);
                    *(float4*)(o + 4) = make_float4(0.f, 0.f, 0.f, 0.f);
                }
            }
            cnt += (int)__builtin_popcountll(mask);
        }
    }
    if (cnt > 32) cnt = 32;
    for (int p2 = cnt + lane; p2 < 32; p2 += 64) {
        float* o = out0 + (size_t)p2 * 8;
        *(float4*)o = make_float4(f0x, f0y, f0z, f0t);
        *(float4*)(o + 4) = make_float4(0.f, 0.f, 0.f, 0.f);
    }
}

// ---------------- query_ball body (SA2 geometry, device) ----------------
__device__ __forceinline__ void qb2_dev(
    const float* __restrict__ xyz, const float* __restrict__ centers,
    int* __restrict__ outIdx, int gw, int lane)
{
    const int N = 512, stride = 3, S = 128, nsample = 64;
    const float r2 = 0.16f;
    int b = gw / S;
    const float* P = xyz + (size_t)b * N * stride;
    float cx = centers[(size_t)gw * 3 + 0];
    float cy = centers[(size_t)gw * 3 + 1];
    float cz = centers[(size_t)gw * 3 + 2];
    int* out = outIdx + (size_t)gw * nsample;
    int cnt = 0;
    int firstIdx = 0;
    bool haveFirst = false;
    for (int base = 0; base < N && cnt < nsample; base += 64) {
        int n = base + lane;
        bool inb = false;
        if (n < N) {
            float dx = __fsub_rn(cx, P[(size_t)n * stride + 0]);
            float dy = __fsub_rn(cy, P[(size_t)n * stride + 1]);
            float dz = __fsub_rn(cz, P[(size_t)n * stride + 2]);
            float d = __fadd_rn(__fadd_rn(__fmul_rn(dx, dx), __fmul_rn(dy, dy)),
                                __fmul_rn(dz, dz));
            inb = !(d > r2);
        }
        unsigned long long mask = __ballot(inb);
        if (mask) {
            if (!haveFirst) { firstIdx = base + __builtin_ctzll(mask); haveFirst = true; }
            if (inb) {
                int pos = cnt + __builtin_popcountll(mask & ((1ull << lane) - 1ull));
                if (pos < nsample) out[pos] = n;
            }
            cnt += (int)__builtin_popcountll(mask);
        }
    }
    if (cnt > nsample) cnt = nsample;
    for (int p = cnt + lane; p < nsample; p += 64) out[p] = firstIdx;
}

// ---------------- fused GEMM: Y/Vmaxmin = act/gather(X) * W^T + stats ------
// gmode 0: X rows direct; gmode 2: group2 inline; gmode 3: group3 inline.
// redK 0: store Y. redK 32/64: per-center max/min of acc rows -> Vmax/Vmin
// (Y not written). Centers are tile-local: K=32 -> c=(wm>>5)+(mt>>1);
// K=64 -> c=wm>>6. Quad-reduce via shfl_xor 16/32; quad==0 lanes write.
// Tail: per-channel block sums via 2x atomicAdd(double) into partS/partQ.
__global__ __launch_bounds__(256) void gemm_fused(
    const float* __restrict__ X,
    const double* __restrict__ pSin, const double* __restrict__ pQin,
    const float* __restrict__ gIn, const float* __restrict__ bIn,
    double invMin, int applyAct,
    const unsigned short* __restrict__ Bh, const unsigned short* __restrict__ Bl,
    float* __restrict__ Y,
    double* __restrict__ pSout, double* __restrict__ pQout,
    int AC, int CPW, int O, int gmode,
    const int* __restrict__ gqb, const float* __restrict__ gxyz,
    const float* __restrict__ gctr, const float* __restrict__ gfeat,
    int redK, float* __restrict__ Vmax, float* __restrict__ Vmin)
{
    constexpr int PITCH = 40;
    __shared__ __align__(16) unsigned short sAh[128 * PITCH];
    __shared__ __align__(16) unsigned short sAl[128 * PITCH];
    __shared__ __align__(16) unsigned short sBh[128 * PITCH];
    __shared__ __align__(16) unsigned short sBl[128 * PITCH];
    __shared__ float sred[2048];
    __shared__ float sScale[512];
    __shared__ float sShift[512];

    const int tid = threadIdx.x;
    const int lane = tid & 63;
    const int wid = tid >> 6;
    const int col15 = lane & 15;
    const int quad = lane >> 4;
    const int wm = (wid >> 1) * 64;
    const int wo = (wid & 1) * 64;
    const int m0 = blockIdx.x * 128;
    const int o0 = blockIdx.y * 128;
    const int lr = tid >> 2;
    const int lc = (tid & 3) * 8;

    // head: derive this layer's input BN scale/shift from summed stats.
    if (applyAct) {
        for (int c = tid; c < AC; c += 256) {
            double S = pSin[c], Q = pQin[c];
            double mean = S * invMin;
            double var = Q * invMin - mean * mean;
            float varf = (float)var;
            if (varf < 0.f) varf = 0.f;
            float sc = gIn[c] * rsqrtf(varf + 1e-5f);
            sScale[c] = sc;
            sShift[c] = bIn[c] - (float)mean * sc;
        }
    }
    __syncthreads();

    f32x4 acc[4][4];
#pragma unroll
    for (int mt = 0; mt < 4; ++mt)
#pragma unroll
        for (int ot = 0; ot < 4; ++ot)
            acc[mt][ot] = {0.f, 0.f, 0.f, 0.f};

    for (int k0 = 0; k0 < CPW; k0 += 32) {
#pragma unroll
        for (int it = 0; it < 2; ++it) {
            int r = lr + it * 64;
            int c = k0 + lc;
            unsigned short h[8], l[8];
            float vv[8];
            bool have = true;
            if (gmode == 0) {
                if (c + 8 <= AC) {
                    const float* xr = X + (size_t)(m0 + r) * AC + c;
                    float4 v0 = *(const float4*)xr;
                    float4 v1 = *(const float4*)(xr + 4);
                    vv[0] = v0.x; vv[1] = v0.y; vv[2] = v0.z; vv[3] = v0.w;
                    vv[4] = v1.x; vv[5] = v1.y; vv[6] = v1.z; vv[7] = v1.w;
                    if (applyAct) {
#pragma unroll
                        for (int j = 0; j < 8; ++j)
                            vv[j] = fmaxf(vv[j] * sScale[c + j] + sShift[c + j], 0.f);
                    }
                } else {
                    have = false;
                }
            } else if (gmode == 2) {
                // group2 inline: row m = sk in (8,128,64) flattened
                int m = m0 + r;
                int idx = gqb[m];
                idx = (idx < 0) ? 0 : (idx > 511 ? 511 : idx);
                int bb2 = m >> 13;          // / (128*64)
                int bs = m >> 6;            // / 64
                const float* frow = gfeat + ((size_t)bb2 * 512 + idx) * 128;
                const float* xrow = gxyz + ((size_t)bb2 * 512 + idx) * 3;
                const float* crow = gctr + (size_t)bs * 3;
#pragma unroll
                for (int j = 0; j < 8; ++j) {
                    int cc = c + j;
                    float v = 0.f;
                    if (cc < 3)        v = __fsub_rn(xrow[cc], crow[cc]);
                    else if (cc < 131) v = frow[cc - 3];
                    vv[j] = v;
                }
            } else {
                // group3 inline: row m = sk in (8*128) == 1024 rows
                int m = m0 + r;
                const float* frow = gfeat + (size_t)m * 256;
                const float* crow = gctr + (size_t)m * 3;
#pragma unroll
                for (int j = 0; j < 8; ++j) {
                    int cc = c + j;
                    float v = 0.f;
                    if (cc < 3)        v = crow[cc];
                    else if (cc < 259) v = frow[cc - 3];
                    vv[j] = v;
                }
            }
            if (have) {
#pragma unroll
                for (int j = 0; j < 8; ++j) f2bf_split(vv[j], h[j], l[j]);
            } else {
#pragma unroll
                for (int j = 0; j < 8; ++j) { h[j] = 0; l[j] = 0; }
            }
            *(ushort4*)&sAh[r * PITCH + lc] = make_ushort4(h[0], h[1], h[2], h[3]);
            *(ushort4*)&sAh[r * PITCH + lc + 4] = make_ushort4(h[4], h[5], h[6], h[7]);
            *(ushort4*)&sAl[r * PITCH + lc] = make_ushort4(l[0], l[1], l[2], l[3]);
            *(ushort4*)&sAl[r * PITCH + lc + 4] = make_ushort4(l[4], l[5], l[6], l[7]);
        }
#pragma unroll
        for (int it = 0; it < 2; ++it) {
            int r = lr + it * 64;
            int c = k0 + lc;
            int o = o0 + r;
            uint4 vh = {0, 0, 0, 0}, vl = {0, 0, 0, 0};
            if (o < O && c < CPW) {
                size_t goff = (size_t)o * CPW + c;
                vh = *(const uint4*)(Bh + goff);
                vl = *(const uint4*)(Bl + goff);
            }
            *(uint4*)&sBh[r * PITCH + lc] = vh;
            *(uint4*)&sBl[r * PITCH + lc] = vl;
        }
        __syncthreads();
        s16x8 ah[4], al[4], bh[4], bl[4];
#pragma unroll
        for (int mt = 0; mt < 4; ++mt) {
            int rowoff = (wm + mt * 16 + col15) * PITCH + quad * 8;
            ah[mt] = *(const s16x8*)&sAh[rowoff];
            al[mt] = *(const s16x8*)&sAl[rowoff];
        }
#pragma unroll
        for (int ot = 0; ot < 4; ++ot) {
            int rowoff = (wo + ot * 16 + col15) * PITCH + quad * 8;
            bh[ot] = *(const s16x8*)&sBh[rowoff];
            bl[ot] = *(const s16x8*)&sBl[rowoff];
        }
#pragma unroll
        for (int mt = 0; mt < 4; ++mt)
#pragma unroll
            for (int ot = 0; ot < 4; ++ot) {
                acc[mt][ot] = __builtin_amdgcn_mfma_f32_16x16x32_bf16(
                    ah[mt], bl[ot], acc[mt][ot], 0, 0, 0);
                acc[mt][ot] = __builtin_amdgcn_mfma_f32_16x16x32_bf16(
                    al[mt], bh[ot], acc[mt][ot], 0, 0, 0);
                acc[mt][ot] = __builtin_amdgcn_mfma_f32_16x16x32_bf16(
                    ah[mt], bh[ot], acc[mt][ot], 0, 0, 0);
            }
        __syncthreads();
    }
    if (redK == 0) {
#pragma unroll
        for (int mt = 0; mt < 4; ++mt)
#pragma unroll
            for (int ot = 0; ot < 4; ++ot) {
                int og = o0 + wo + ot * 16 + col15;
                if (og < O) {
#pragma unroll
                    for (int r = 0; r < 4; ++r) {
                        int mg = m0 + wm + mt * 16 + quad * 4 + r;
                        Y[(size_t)mg * O + og] = acc[mt][ot][r];
                    }
                }
            }
    } else if (redK == 32) {
        // 4 centers / 128-row tile; center-local = (wm>>5) + (mt>>1).
#pragma unroll
        for (int ot = 0; ot < 4; ++ot) {
            int og = o0 + wo + ot * 16 + col15;
#pragma unroll
            for (int cp = 0; cp < 2; ++cp) {
                float mx = acc[2 * cp][ot][0];
                float mn = mx;
#pragma unroll
                for (int mi = 0; mi < 2; ++mi)
#pragma unroll
                    for (int r = 0; r < 4; ++r) {
                        float v = acc[2 * cp + mi][ot][r];
                        mx = fmaxf(mx, v);
                        mn = fminf(mn, v);
                    }
                mx = fmaxf(mx, __shfl_xor(mx, 16));
                mx = fmaxf(mx, __shfl_xor(mx, 32));
                mn = fminf(mn, __shfl_xor(mn, 16));
                mn = fminf(mn, __shfl_xor(mn, 32));
                if (quad == 0) {
                    int ctr = (m0 >> 5) + (wm >> 5) + cp;
                    Vmax[(size_t)ctr * O + og] = mx;
                    Vmin[(size_t)ctr * O + og] = mn;
                }
            }
        }
    } else {   // redK == 64: 2 centers / tile; center-local = wm>>6.
#pragma unroll
        for (int ot = 0; ot < 4; ++ot) {
            int og = o0 + wo + ot * 16 + col15;
            float mx = acc[0][ot][0];
            float mn = mx;
#pragma unroll
            for (int mt = 0; mt < 4; ++mt)
#pragma unroll
                for (int r = 0; r < 4; ++r) {
                    float v = acc[mt][ot][r];
                    mx = fmaxf(mx, v);
                    mn = fminf(mn, v);
                }
            mx = fmaxf(mx, __shfl_xor(mx, 16));
            mx = fmaxf(mx, __shfl_xor(mx, 32));
            mn = fminf(mn, __shfl_xor(mn, 16));
            mn = fminf(mn, __shfl_xor(mn, 32));
            if (quad == 0) {
                int ctr = (m0 >> 6) + (wm >> 6);
                Vmax[(size_t)ctr * O + og] = mx;
                Vmin[(size_t)ctr * O + og] = mn;
            }
        }
    }
    // BN stats epilogue (R13-identical fixed-order block combine), then two
    // f64 atomicAdds per channel (simple tail — no register-pressure bomb).
#pragma unroll
    for (int ot = 0; ot < 4; ++ot) {
        float s = 0.f, s2 = 0.f;
#pragma unroll
        for (int mt = 0; mt < 4; ++mt)
#pragma unroll
            for (int r = 0; r < 4; ++r) {
                float v = acc[mt][ot][r];
                s += v;
                s2 += v * v;
            }
        int slot = ((wid * 4 + quad) * 16 + col15) * 4 + ot;
        sred[slot * 2] = s;
        sred[slot * 2 + 1] = s2;
    }
    __syncthreads();
    if (tid < 128) {
        int col = tid;
        int o = o0 + col;
        if (o < O) {
            int cb = col >> 6;
            int ot = (col & 63) >> 4;
            int c15 = col & 15;
            double S = 0.0, S2 = 0.0;
#pragma unroll
            for (int wp = 0; wp < 2; ++wp) {
                int wd = cb + wp * 2;
#pragma unroll
                for (int q = 0; q < 4; ++q) {
                    int slot = ((wd * 4 + q) * 16 + c15) * 4 + ot;
                    S += (double)sred[slot * 2];
                    S2 += (double)sred[slot * 2 + 1];
                }
            }
            atomicAdd(&pSout[o], S);
            atomicAdd(&pQout[o], S2);
        }
    }
}

// ---------------- BN + ReLU + max over K (+ optional SA2 query_ball) -------
// vmode 0: loop K rows of Y. vmode 1: read Vmax/Vmin (Y=Vmax) — monotone
// selection: v = sc>=0 ? vmax : vmin; out = relu(v*sc+sh). Exact.
__global__ __launch_bounds__(256) void bn_relu_max(
    const float* __restrict__ Y, const float* __restrict__ Vmin,
    const double* __restrict__ pS, const double* __restrict__ pQ,
    const float* __restrict__ gv, const float* __restrict__ bv, double invM,
    float* __restrict__ out, int Stot, int K, int O, int vmode, int nMain,
    const float* __restrict__ qbXyz, const float* __restrict__ qbCtr,
    int* __restrict__ qbOut)
{
    if ((int)blockIdx.x >= nMain) {   // piggyback: SA2 query_ball (4 waves)
        int wid = threadIdx.x >> 6, lane = threadIdx.x & 63;
        int gw = ((int)blockIdx.x - nMain) * 4 + wid;
        if (gw < 1024) qb2_dev(qbXyz, qbCtr, qbOut, gw, lane);
        return;
    }
    int idx = blockIdx.x * 256 + threadIdx.x;
    if (idx >= Stot * O) return;
    int s = idx / O;
    int o = idx - s * O;
    double S = pS[o], Q = pQ[o];
    double mean = S * invM;
    double var = Q * invM - mean * mean;
    float varf = (float)var;
    if (varf < 0.f) varf = 0.f;
    float sc = gv[o] * rsqrtf(varf + 1e-5f);
    float sh = bv[o] - (float)mean * sc;
    if (vmode) {
        float vmax = Y[(size_t)s * O + o];
        float vmin = Vmin[(size_t)s * O + o];
        float v = (sc >= 0.f) ? vmax : vmin;
        out[idx] = fmaxf(v * sc + sh, 0.f);
        return;
    }
    const float* basep = Y + (size_t)s * K * O + o;
    float mx = 0.f;
    for (int k = 0; k < K; ++k) {
        float v = basep[(size_t)k * O] * sc + sh;
        v = fmaxf(v, 0.f);
        mx = fmaxf(mx, v);
    }
    out[idx] = mx;
}

// ============================================================================
extern "C" void kernel_launch(void* const* d_in, const int* in_sizes, int n_in,
                              void* d_out, int out_size, void* d_ws, size_t ws_size,
                              hipStream_t stream)
{
    const float* xin = (const float*)d_in[0];
    const float* w[9]; const float* g[9]; const float* bb[9];
    for (int i = 0; i < 9; ++i) {
        w[i]  = (const float*)d_in[1 + 3 * i];
        g[i]  = (const float*)d_in[2 + 3 * i];
        bb[i] = (const float*)d_in[3 + 3 * i];
    }

    char* base = (char*)d_ws;
    size_t off = 0;
    auto alloc = [&](size_t bytes) -> void* {
        void* p = base + off;
        off = (off + bytes + 255) & ~(size_t)255;
        return p;
    };
    const int OC[9][3] = {{64,4,8},{64,64,64},{128,64,64},
                          {128,131,136},{128,128,128},{256,128,128},
                          {256,259,264},{512,256,256},{1024,512,512}};
    size_t woff[10]; woff[0] = 0;
    for (int i = 0; i < 9; ++i) woff[i + 1] = woff[i] + (size_t)OC[i][0] * OC[i][2];

    // --- small / metadata region (memset-protected) ---
    int*    fps1   = (int*)alloc((size_t)4096 * 4);
    int*    fps2   = (int*)alloc((size_t)1024 * 4);
    int*    qb2    = (int*)alloc((size_t)65536 * 4);
    float*  nx1    = (float*)alloc((size_t)12288 * 4);
    float*  nx2    = (float*)alloc((size_t)3072 * 4);
    float*  feat1  = (float*)alloc((size_t)524288 * 4);
    float*  feat2  = (float*)alloc((size_t)262144 * 4);
    double* partS  = (double*)alloc((size_t)9 * 1024 * 8);   // per-layer sums
    double* partQ  = (double*)alloc((size_t)9 * 1024 * 8);   // per-layer sumsq
    unsigned short* WH = (unsigned short*)alloc(woff[9] * 2);
    unsigned short* WL = (unsigned short*)alloc(woff[9] * 2);
    const size_t zeroBytes = off;
    // --- big ping/pong buffers (fully written before read at every use) ---
    float*  XG = (float*)alloc((size_t)65536 * 136 * 4);
    float*  A  = (float*)alloc((size_t)16777216 * 4);
    if (off > ws_size) return;

    // Defensive zero of the metadata region only (~5 MB): indices and the
    // per-layer stat accumulators start at 0 every invocation.
    hipMemsetAsync(d_ws, 0, zeroBytes, stream);

    PWArgs pwa;
    for (int i = 0; i < 9; ++i) {
        pwa.w[i] = w[i]; pwa.off[i] = (unsigned)woff[i];
        pwa.O[i] = OC[i][0]; pwa.C[i] = OC[i][1]; pwa.CP[i] = OC[i][2];
    }
    const int nPrep = (int)((woff[9] + 255) / 256);

    auto gemm = [&](const float* X, int prevLi, double invMprev, int li,
                    float* Y, int YB, int OB, int AC, int CPW, int O,
                    int gmode, const int* gqb, const float* gxyz,
                    const float* gctr, const float* gfeat,
                    int redK, float* Vmax, float* Vmin) {
        gemm_fused<<<dim3(YB, OB), 256, 0, stream>>>(
            X,
            prevLi >= 0 ? partS + (size_t)prevLi * 1024 : nullptr,
            prevLi >= 0 ? partQ + (size_t)prevLi * 1024 : nullptr,
            prevLi >= 0 ? g[prevLi] : nullptr,
            prevLi >= 0 ? bb[prevLi] : nullptr,
            invMprev, prevLi >= 0 ? 1 : 0,
            WH + woff[li], WL + woff[li], Y,
            partS + (size_t)li * 1024, partQ + (size_t)li * 1024,
            AC, CPW, O, gmode, gqb, gxyz, gctr, gfeat, redK, Vmax, Vmin);
    };

    const double inv1 = 1.0 / 131072.0;
    const double inv2 = 1.0 / 65536.0;
    const double inv3 = 1.0 / 1024.0;

    // ---------------- SA1 ----------------
    fps_block<256, 16, 4><<<8 + nPrep, 256, 0, stream>>>(
        xin, 512, fps1, nx1, 8, pwa, WH, WL, (int)woff[9]);
    // qb_group1 blocks 0-1023: group; 1024-1031: SA2 single-wave FPS.
    qb_group1<<<1024 + 8, 256, 0, stream>>>(xin, nx1, XG, 1024, nx1, fps2, nx2);

    gemm(XG, -1, 0.0, 0, A, 1024, 1, 8, 8, 64, 0, nullptr, nullptr, nullptr, nullptr, 0, nullptr, nullptr);
    gemm(A, 0, inv1, 1, XG, 1024, 1, 64, 64, 64, 0, nullptr, nullptr, nullptr, nullptr, 0, nullptr, nullptr);
    // L1_2: K=32 reduce mode — Vmax/Vmin (4096x128) into A, no Y write.
    gemm(XG, 1, inv1, 2, A, 1024, 1, 64, 64, 128, 0, nullptr, nullptr, nullptr, nullptr, 32, A, A + 524288);
    // bn_relu_max vmode=1 (2048 blocks) + SA2 query_ball (256 blocks) fused.
    bn_relu_max<<<2048 + 256, 256, 0, stream>>>(
        A, A + 524288, partS + 2 * 1024, partQ + 2 * 1024, g[2], bb[2], inv1,
        feat1, 4096, 32, 128, 1, 2048, nx1, nx2, qb2);

    // ---------------- SA2 ----------------
    // L2_0: A-staging gathers group2 inline (qb2/nx1/feat1) — no XG pass.
    gemm(nullptr, -1, 0.0, 3, A, 512, 1, 136, 136, 128, 2, qb2, nx1, nx2, feat1, 0, nullptr, nullptr);
    gemm(A, 3, inv2, 4, XG, 512, 1, 128, 128, 128, 0, nullptr, nullptr, nullptr, nullptr, 0, nullptr, nullptr);
    // L2_2: K=64 reduce mode — Vmax/Vmin (1024x256) into A, no Y write.
    gemm(XG, 4, inv2, 5, A, 512, 2, 128, 128, 256, 0, nullptr, nullptr, nullptr, nullptr, 64, A, A + 262144);
    bn_relu_max<<<(1024 * 256) / 256, 256, 0, stream>>>(
        A, A + 262144, partS + 5 * 1024, partQ + 5 * 1024, g[5], bb[5], inv2,
        feat2, 1024, 64, 256, 1, 1024 * 256 / 256, nullptr, nullptr, nullptr);

    // ---------------- SA3 (group_all) ----------------
    // L3_0: A-staging gathers group3 inline (nx2/feat2) — no XG pass.
    gemm(nullptr, -1, 0.0, 6, A, 8, 2, 264, 264, 256, 3, nullptr, nullptr, nx2, feat2, 0, nullptr, nullptr);
    gemm(A, 6, inv3, 7, XG, 8, 4, 256, 256, 512, 0, nullptr, nullptr, nullptr, nullptr, 0, nullptr, nullptr);
    gemm(XG, 7, inv3, 8, A, 8, 8, 512, 512, 1024, 0, nullptr, nullptr, nullptr, nullptr, 0, nullptr, nullptr);
    bn_relu_max<<<(8 * 1024) / 256, 256, 0, stream>>>(
        A, nullptr, partS + 8 * 1024, partQ + 8 * 1024, g[8], bb[8], inv3,
        (float*)d_out, 8, 128, 1024, 0, (8 * 1024) / 256,
        nullptr, nullptr, nullptr);
}

// Round 13
// 767.047 us; speedup vs baseline: 1.0780x; 1.0362x over previous
//
#include <hip/hip_runtime.h>

// ============================================================================
// TemporalPointNet (PointNet++ style) forward on MI355X.
// B=2, T=4 -> BT=8 "batches", N=4096 points, 4 coords (xyz + t).
// SA1: npoint=512, r=0.2, K=32, C_in=4,  MLP 64,64,128
// SA2: npoint=128, r=0.4, K=64, C_in=131, MLP 128,128,256
// SA3: group_all,          K=128, C_in=259, MLP 256,512,1024
//
// R25 = R24 (795us, best) + L1_0 folded into qb_group1:
//  - L1_0 is a K=4 matmul; its input rows are BORN inside qb_group1. The
//    wave now keeps its center's 32 rows in LDS (2KB) and computes the
//    64-channel output on the VALU (lane=channel, 32 rows x 4 FMA), writing
//    Y(=A) directly + per-channel stats via the proven lean f64-atomicAdd
//    tail. Plain f32 FMA >= accuracy of the replaced split-bf16 MFMA.
//    Padding rows included in matmul+stats (reference semantics). Removes
//    the 1024-block L1_0 gemm dispatch and the XG 4.2MB round-trip.
//  - Dispatches 14 -> 13.
// R24 retained: in-gemm K-reduction (redK 32/64) for L1_2/L2_2 + vmode
// bn_relu_max (exact monotone max/min selection). R23/R21/R20 retained:
// gather-in-gemm (gmode 2/3); BN stats via 2x f64 atomicAdd + consumer-side
// scale/shift (no fences — R18 +991us; no complex tails — R19 VGPR collapse);
// prep_w piggyback in fps_block; fps_wave piggyback in qb_group1;
// bn_relu_max+SA2-query_ball fusion. FPS chains byte-identical to R11/R13
// measured-best (286us); per-iteration chain is a no-touch zone (R10/R12).
// ============================================================================

typedef short s16x8 __attribute__((ext_vector_type(8)));
typedef float f32x4 __attribute__((ext_vector_type(4)));

__device__ __forceinline__ unsigned short f2bf_rne(float f) {
    unsigned u = __float_as_uint(f);
    u += 0x7FFFu + ((u >> 16) & 1u);
    return (unsigned short)(u >> 16);
}
// split f32 -> (hi, lo) bf16 pair: hi = rne(v), lo = rne(v - hi)
__device__ __forceinline__ void f2bf_split(float v, unsigned short& hi,
                                           unsigned short& lo) {
    unsigned u = __float_as_uint(v);
    unsigned r = u + 0x7FFFu + ((u >> 16) & 1u);
    hi = (unsigned short)(r >> 16);
    float vh = __uint_as_float(r & 0xFFFF0000u);
    lo = f2bf_rne(v - vh);
}

__device__ __forceinline__ unsigned long long umax64(unsigned long long a,
                                                     unsigned long long b) {
    return a > b ? a : b;
}

// Wave64 max-reduce via DPP: 1 DPP + 1 max per step (R9 measured-best;
// R10/R12 variants regressed — do not touch).
__device__ __forceinline__ unsigned wred_umax63(unsigned v) {
    unsigned t;
    t = (unsigned)__builtin_amdgcn_update_dpp(0, (int)v, 0x111, 0xf, 0xf, true); if (t > v) v = t;
    t = (unsigned)__builtin_amdgcn_update_dpp(0, (int)v, 0x112, 0xf, 0xf, true); if (t > v) v = t;
    t = (unsigned)__builtin_amdgcn_update_dpp(0, (int)v, 0x114, 0xf, 0xf, true); if (t > v) v = t;
    t = (unsigned)__builtin_amdgcn_update_dpp(0, (int)v, 0x118, 0xf, 0xf, true); if (t > v) v = t;
    t = (unsigned)__builtin_amdgcn_update_dpp(0, (int)v, 0x142, 0xa, 0xf, true); if (t > v) v = t;
    t = (unsigned)__builtin_amdgcn_update_dpp(0, (int)v, 0x143, 0xc, 0xf, true); if (t > v) v = t;
    return v;
}

// Wave argmax of (dist, min-index). Exact first-occurrence argmax.
__device__ __forceinline__ void wave_argmax(unsigned dbits, unsigned nInv,
                                            unsigned& vmax, unsigned& iInv) {
    unsigned m = wred_umax63(dbits);
    vmax = (unsigned)__builtin_amdgcn_readlane((int)m, 63);
    unsigned cand = (dbits == vmax) ? nInv : 0u;
    unsigned im = wred_umax63(cand);
    iInv = (unsigned)__builtin_amdgcn_readlane((int)im, 63);
}

// ---------------- all-layer weight pre-split (device body) ----------------
struct PWArgs {
    const float* w[9];
    unsigned off[9];
    int O[9], C[9], CP[9];
};
__device__ __forceinline__ void prep_w_dev(const PWArgs& a,
                                           unsigned short* __restrict__ wh,
                                           unsigned short* __restrict__ wl,
                                           int i) {
    int l = 0;
#pragma unroll
    for (int k = 1; k < 9; ++k) if (i >= (int)a.off[k]) l = k;
    int li = i - (int)a.off[l];
    int CP = a.CP[l];
    int o = li / CP;
    int c = li - o * CP;
    float v = (c < a.C[l]) ? a.w[l][(size_t)o * a.C[l] + c] : 0.f;
    unsigned short h, lo;
    f2bf_split(v, h, lo);
    wh[i] = h; wl[i] = lo;
}

// ---------------- FPS (multi-wave): one block (NT thr) per batch ------------
// R7/R9 structure (measured best 286us). Blocks >= nFps run the weight
// pre-split (fully hidden in the FPS shadow).
template<int NT, int ITEMS, int STRIDE>
__global__ __launch_bounds__(NT) void fps_block(
    const float* __restrict__ pts, int npoint,
    int* __restrict__ outIdx, float* __restrict__ outXyz,
    int nFps, PWArgs pw, unsigned short* __restrict__ wh,
    unsigned short* __restrict__ wl, int wtotal)
{
    constexpr int N = NT * ITEMS;
    constexpr int NW = NT / 64;
    __shared__ float4 scoord[N];
    __shared__ unsigned long long wkey[2][NW];

    if (blockIdx.x >= nFps) {   // piggyback: weight split on idle CUs
        int i = (blockIdx.x - nFps) * NT + threadIdx.x;
        if (i < wtotal) prep_w_dev(pw, wh, wl, i);
        return;
    }

    const int b = blockIdx.x;
    const int tid = threadIdx.x;
    const int wid = tid >> 6;
    const int lane = tid & 63;
    const float* P = pts + (size_t)b * N * STRIDE;

    float px[ITEMS], py[ITEMS], pz[ITEMS], dloc[ITEMS];
#pragma unroll
    for (int w = 0; w < ITEMS; ++w) {
        int n = tid + w * NT;
        float x, y, z;
        if (STRIDE == 4) {
            float4 v = *(const float4*)(P + (size_t)n * 4);
            x = v.x; y = v.y; z = v.z;
        } else {
            x = P[(size_t)n * STRIDE + 0];
            y = P[(size_t)n * STRIDE + 1];
            z = P[(size_t)n * STRIDE + 2];
        }
        px[w] = x; py[w] = y; pz[w] = z;
        scoord[n] = make_float4(x, y, z, 0.f);
        dloc[w] = 1e10f;
    }
    __syncthreads();
    float4 c0 = scoord[0];
    float cx = c0.x, cy = c0.y, cz = c0.z;
    int far = 0;

    for (int i = 0; i < npoint; ++i) {
        if (tid == 0) {
            outIdx[(size_t)b * npoint + i] = far;
            outXyz[((size_t)b * npoint + i) * 3 + 0] = cx;
            outXyz[((size_t)b * npoint + i) * 3 + 1] = cy;
            outXyz[((size_t)b * npoint + i) * 3 + 2] = cz;
        }
        float bestV = -1.0f;
        int bestW = 0;
#pragma unroll
        for (int w = 0; w < ITEMS; ++w) {
            float dx = __fsub_rn(px[w], cx);
            float dy = __fsub_rn(py[w], cy);
            float dz = __fsub_rn(pz[w], cz);
            float d = __fadd_rn(__fadd_rn(__fmul_rn(dx, dx), __fmul_rn(dy, dy)),
                                __fmul_rn(dz, dz));
            float dd = fminf(dloc[w], d);
            dloc[w] = dd;
            if (dd > bestV) { bestV = dd; bestW = w; }  // strict > : lowest w kept
        }
        int bestN = tid + bestW * NT;   // n grows with w -> min n on tie
        unsigned vmax, iInv;
        wave_argmax(__float_as_uint(bestV), 0xFFFFFFFFu ^ (unsigned)bestN,
                    vmax, iInv);
        const int par = i & 1;
        if (lane == 0)
            wkey[par][wid] = ((unsigned long long)vmax << 32) | iInv;
        __syncthreads();   // single barrier per iteration (parity dbuf)
        unsigned long long kb = wkey[par][0];
#pragma unroll
        for (int w2 = 1; w2 < NW; ++w2) kb = umax64(kb, wkey[par][w2]);
        far = (int)(0xFFFFFFFFu ^ (unsigned)kb);
        float4 cc = scoord[far];   // broadcast, conflict-free
        cx = cc.x; cy = cc.y; cz = cc.z;
    }
}

// ---------------- FPS (single wave, device body, no barriers) ---------------
__device__ void fps_wave_dev(const float* __restrict__ pts, int npoint,
                             int* __restrict__ outIdx, float* __restrict__ outXyz,
                             int b, float4* scoord)
{
    constexpr int ITEMS = 8;
    constexpr int STRIDE = 3;
    constexpr int N = 64 * ITEMS;
    const int tid = threadIdx.x;   // 0..63
    const float* P = pts + (size_t)b * N * STRIDE;

    float px[ITEMS], py[ITEMS], pz[ITEMS], dloc[ITEMS];
#pragma unroll
    for (int w = 0; w < ITEMS; ++w) {
        int n = tid + w * 64;
        float x = P[(size_t)n * STRIDE + 0];
        float y = P[(size_t)n * STRIDE + 1];
        float z = P[(size_t)n * STRIDE + 2];
        px[w] = x; py[w] = y; pz[w] = z;
        scoord[n] = make_float4(x, y, z, 0.f);
        dloc[w] = 1e10f;
    }
    __threadfence_block();
    float4 c0 = scoord[0];
    float cx = c0.x, cy = c0.y, cz = c0.z;
    int far = 0;

    for (int i = 0; i < npoint; ++i) {
        if (tid == 0) {
            outIdx[(size_t)b * npoint + i] = far;
            outXyz[((size_t)b * npoint + i) * 3 + 0] = cx;
            outXyz[((size_t)b * npoint + i) * 3 + 1] = cy;
            outXyz[((size_t)b * npoint + i) * 3 + 2] = cz;
        }
        float bestV = -1.0f;
        int bestW = 0;
#pragma unroll
        for (int w = 0; w < ITEMS; ++w) {
            float dx = __fsub_rn(px[w], cx);
            float dy = __fsub_rn(py[w], cy);
            float dz = __fsub_rn(pz[w], cz);
            float d = __fadd_rn(__fadd_rn(__fmul_rn(dx, dx), __fmul_rn(dy, dy)),
                                __fmul_rn(dz, dz));
            float dd = fminf(dloc[w], d);
            dloc[w] = dd;
            if (dd > bestV) { bestV = dd; bestW = w; }
        }
        int bestN = tid + bestW * 64;
        unsigned vmax, iInv;
        wave_argmax(__float_as_uint(bestV), 0xFFFFFFFFu ^ (unsigned)bestN,
                    vmax, iInv);
        far = (int)(0xFFFFFFFFu ^ iInv);
        float4 cc = scoord[far];
        cx = cc.x; cy = cc.y; cz = cc.z;
    }
}

// ---------------- fused query_ball + group + L1_0 for SA1 ------------------
// One wave per center. Scan identical to R24 (e = p - c; rows in ascending
// point order; padding = first in-ball row). Rows kept in LDS (2KB/wave);
// then L1_0 computed on the VALU: lane = channel, y = ex*w0+ey*w1+ez*w2+t*w3
// over 32 rows (padding rows included — reference BN semantics), written to
// Y(=A) + per-channel stats -> f64 atomicAdd (lean tail). f32 FMA accuracy
// >= the replaced split-bf16 MFMA. Blocks >= nQb: fps_wave piggyback.
__global__ __launch_bounds__(256) void qb_group1(
    const float* __restrict__ xyz /*(8,4096,4)*/,
    const float* __restrict__ ctr /*(8*512,3)*/,
    const float* __restrict__ W0 /*(64,4)*/,
    float* __restrict__ Yout /*(131072,64)*/,
    double* __restrict__ pS0, double* __restrict__ pQ0,
    int nQb, const float* __restrict__ fpsPts,
    int* __restrict__ fpsIdx, float* __restrict__ fpsXyz)
{
    __shared__ float4 scoord[512];
    __shared__ float4 srows[4][32];
    __shared__ float sstat[4][64][2];
    if ((int)blockIdx.x >= nQb) {   // piggyback: single-wave FPS (SA2)
        if (threadIdx.x < 64)
            fps_wave_dev(fpsPts, 128, fpsIdx, fpsXyz,
                         (int)blockIdx.x - nQb, scoord);
        return;
    }
    const int tid = threadIdx.x;
    const int gw = (blockIdx.x * 256 + tid) >> 6;   // < 4096 for all nQb blocks
    const int wid = tid >> 6;
    const int lane = tid & 63;
    int b = gw >> 9;
    const float* P = xyz + (size_t)b * 4096 * 4;
    float cx = ctr[(size_t)gw * 3 + 0];
    float cy = ctr[(size_t)gw * 3 + 1];
    float cz = ctr[(size_t)gw * 3 + 2];
    int cnt = 0;
    float f0x = 0.f, f0y = 0.f, f0z = 0.f, f0t = 0.f;
    bool haveFirst = false;
    for (int base = 0; base < 4096 && cnt < 32; base += 64) {
        int n = base + lane;
        float4 p = *(const float4*)(P + (size_t)n * 4);
        float ex = __fsub_rn(p.x, cx);
        float ey = __fsub_rn(p.y, cy);
        float ez = __fsub_rn(p.z, cz);
        float d = __fadd_rn(__fadd_rn(__fmul_rn(ex, ex), __fmul_rn(ey, ey)),
                            __fmul_rn(ez, ez));
        bool inb = !(d > 0.04f);
        unsigned long long mask = __ballot(inb);
        if (mask) {
            if (!haveFirst) {
                int fl = (int)__builtin_ctzll(mask);   // wave-uniform
                f0x = __shfl(ex, fl); f0y = __shfl(ey, fl);
                f0z = __shfl(ez, fl); f0t = __shfl(p.w, fl);
                haveFirst = true;
            }
            if (inb) {
                int pos = cnt + __builtin_popcountll(mask & ((1ull << lane) - 1ull));
                if (pos < 32)
                    srows[wid][pos] = make_float4(ex, ey, ez, p.w);
            }
            cnt += (int)__builtin_popcountll(mask);
        }
    }
    if (cnt > 32) cnt = 32;
    for (int p2 = cnt + lane; p2 < 32; p2 += 64)
        srows[wid][p2] = make_float4(f0x, f0y, f0z, f0t);
    __syncthreads();

    // ---- L1_0: lane == output channel; 32 rows x 4 FMA ----
    float wc0 = W0[lane * 4 + 0];
    float wc1 = W0[lane * 4 + 1];
    float wc2 = W0[lane * 4 + 2];
    float wc3 = W0[lane * 4 + 3];
    float s = 0.f, s2 = 0.f;
    float* yp = Yout + (size_t)gw * 32 * 64 + lane;
#pragma unroll 4
    for (int r = 0; r < 32; ++r) {
        float4 e = srows[wid][r];
        float y = e.x * wc0 + e.y * wc1 + e.z * wc2 + e.w * wc3;
        yp[(size_t)r * 64] = y;
        s += y;
        s2 += y * y;
    }
    sstat[wid][lane][0] = s;
    sstat[wid][lane][1] = s2;
    __syncthreads();
    if (tid < 64) {
        double S = 0.0, S2 = 0.0;
#pragma unroll
        for (int w2 = 0; w2 < 4; ++w2) {
            S += (double)sstat[w2][tid][0];
            S2 += (double)sstat[w2][tid][1];
        }
        atomicAdd(&pS0[tid], S);
        atomicAdd(&pQ0[tid], S2);
    }
}

// ---------------- query_ball body (SA2 geometry, device) ----------------
__device__ __forceinline__ void qb2_dev(
    const float* __restrict__ xyz, const float* __restrict__ centers,
    int* __restrict__ outIdx, int gw, int lane)
{
    const int N = 512, stride = 3, S = 128, nsample = 64;
    const float r2 = 0.16f;
    int b = gw / S;
    const float* P = xyz + (size_t)b * N * stride;
    float cx = centers[(size_t)gw * 3 + 0];
    float cy = centers[(size_t)gw * 3 + 1];
    float cz = centers[(size_t)gw * 3 + 2];
    int* out = outIdx + (size_t)gw * nsample;
    int cnt = 0;
    int firstIdx = 0;
    bool haveFirst = false;
    for (int base = 0; base < N && cnt < nsample; base += 64) {
        int n = base + lane;
        bool inb = false;
        if (n < N) {
            float dx = __fsub_rn(cx, P[(size_t)n * stride + 0]);
            float dy = __fsub_rn(cy, P[(size_t)n * stride + 1]);
            float dz = __fsub_rn(cz, P[(size_t)n * stride + 2]);
            float d = __fadd_rn(__fadd_rn(__fmul_rn(dx, dx), __fmul_rn(dy, dy)),
                                __fmul_rn(dz, dz));
            inb = !(d > r2);
        }
        unsigned long long mask = __ballot(inb);
        if (mask) {
            if (!haveFirst) { firstIdx = base + __builtin_ctzll(mask); haveFirst = true; }
            if (inb) {
                int pos = cnt + __builtin_popcountll(mask & ((1ull << lane) - 1ull));
                if (pos < nsample) out[pos] = n;
            }
            cnt += (int)__builtin_popcountll(mask);
        }
    }
    if (cnt > nsample) cnt = nsample;
    for (int p = cnt + lane; p < nsample; p += 64) out[p] = firstIdx;
}

// ---------------- fused GEMM: Y/Vmaxmin = act/gather(X) * W^T + stats ------
// gmode 0: X rows direct; gmode 2: group2 inline; gmode 3: group3 inline.
// redK 0: store Y. redK 32/64: per-center max/min of acc rows -> Vmax/Vmin
// (Y not written). Centers are tile-local: K=32 -> c=(wm>>5)+(mt>>1);
// K=64 -> c=wm>>6. Quad-reduce via shfl_xor 16/32; quad==0 lanes write.
// Tail: per-channel block sums via 2x atomicAdd(double) into partS/partQ.
__global__ __launch_bounds__(256) void gemm_fused(
    const float* __restrict__ X,
    const double* __restrict__ pSin, const double* __restrict__ pQin,
    const float* __restrict__ gIn, const float* __restrict__ bIn,
    double invMin, int applyAct,
    const unsigned short* __restrict__ Bh, const unsigned short* __restrict__ Bl,
    float* __restrict__ Y,
    double* __restrict__ pSout, double* __restrict__ pQout,
    int AC, int CPW, int O, int gmode,
    const int* __restrict__ gqb, const float* __restrict__ gxyz,
    const float* __restrict__ gctr, const float* __restrict__ gfeat,
    int redK, float* __restrict__ Vmax, float* __restrict__ Vmin)
{
    constexpr int PITCH = 40;
    __shared__ __align__(16) unsigned short sAh[128 * PITCH];
    __shared__ __align__(16) unsigned short sAl[128 * PITCH];
    __shared__ __align__(16) unsigned short sBh[128 * PITCH];
    __shared__ __align__(16) unsigned short sBl[128 * PITCH];
    __shared__ float sred[2048];
    __shared__ float sScale[512];
    __shared__ float sShift[512];

    const int tid = threadIdx.x;
    const int lane = tid & 63;
    const int wid = tid >> 6;
    const int col15 = lane & 15;
    const int quad = lane >> 4;
    const int wm = (wid >> 1) * 64;
    const int wo = (wid & 1) * 64;
    const int m0 = blockIdx.x * 128;
    const int o0 = blockIdx.y * 128;
    const int lr = tid >> 2;
    const int lc = (tid & 3) * 8;

    // head: derive this layer's input BN scale/shift from summed stats.
    if (applyAct) {
        for (int c = tid; c < AC; c += 256) {
            double S = pSin[c], Q = pQin[c];
            double mean = S * invMin;
            double var = Q * invMin - mean * mean;
            float varf = (float)var;
            if (varf < 0.f) varf = 0.f;
            float sc = gIn[c] * rsqrtf(varf + 1e-5f);
            sScale[c] = sc;
            sShift[c] = bIn[c] - (float)mean * sc;
        }
    }
    __syncthreads();

    f32x4 acc[4][4];
#pragma unroll
    for (int mt = 0; mt < 4; ++mt)
#pragma unroll
        for (int ot = 0; ot < 4; ++ot)
            acc[mt][ot] = {0.f, 0.f, 0.f, 0.f};

    for (int k0 = 0; k0 < CPW; k0 += 32) {
#pragma unroll
        for (int it = 0; it < 2; ++it) {
            int r = lr + it * 64;
            int c = k0 + lc;
            unsigned short h[8], l[8];
            float vv[8];
            bool have = true;
            if (gmode == 0) {
                if (c + 8 <= AC) {
                    const float* xr = X + (size_t)(m0 + r) * AC + c;
                    float4 v0 = *(const float4*)xr;
                    float4 v1 = *(const float4*)(xr + 4);
                    vv[0] = v0.x; vv[1] = v0.y; vv[2] = v0.z; vv[3] = v0.w;
                    vv[4] = v1.x; vv[5] = v1.y; vv[6] = v1.z; vv[7] = v1.w;
                    if (applyAct) {
#pragma unroll
                        for (int j = 0; j < 8; ++j)
                            vv[j] = fmaxf(vv[j] * sScale[c + j] + sShift[c + j], 0.f);
                    }
                } else {
                    have = false;
                }
            } else if (gmode == 2) {
                // group2 inline: row m = sk in (8,128,64) flattened
                int m = m0 + r;
                int idx = gqb[m];
                idx = (idx < 0) ? 0 : (idx > 511 ? 511 : idx);
                int bb2 = m >> 13;          // / (128*64)
                int bs = m >> 6;            // / 64
                const float* frow = gfeat + ((size_t)bb2 * 512 + idx) * 128;
                const float* xrow = gxyz + ((size_t)bb2 * 512 + idx) * 3;
                const float* crow = gctr + (size_t)bs * 3;
#pragma unroll
                for (int j = 0; j < 8; ++j) {
                    int cc = c + j;
                    float v = 0.f;
                    if (cc < 3)        v = __fsub_rn(xrow[cc], crow[cc]);
                    else if (cc < 131) v = frow[cc - 3];
                    vv[j] = v;
                }
            } else {
                // group3 inline: row m = sk in (8*128) == 1024 rows
                int m = m0 + r;
                const float* frow = gfeat + (size_t)m * 256;
                const float* crow = gctr + (size_t)m * 3;
#pragma unroll
                for (int j = 0; j < 8; ++j) {
                    int cc = c + j;
                    float v = 0.f;
                    if (cc < 3)        v = crow[cc];
                    else if (cc < 259) v = frow[cc - 3];
                    vv[j] = v;
                }
            }
            if (have) {
#pragma unroll
                for (int j = 0; j < 8; ++j) f2bf_split(vv[j], h[j], l[j]);
            } else {
#pragma unroll
                for (int j = 0; j < 8; ++j) { h[j] = 0; l[j] = 0; }
            }
            *(ushort4*)&sAh[r * PITCH + lc] = make_ushort4(h[0], h[1], h[2], h[3]);
            *(ushort4*)&sAh[r * PITCH + lc + 4] = make_ushort4(h[4], h[5], h[6], h[7]);
            *(ushort4*)&sAl[r * PITCH + lc] = make_ushort4(l[0], l[1], l[2], l[3]);
            *(ushort4*)&sAl[r * PITCH + lc + 4] = make_ushort4(l[4], l[5], l[6], l[7]);
        }
#pragma unroll
        for (int it = 0; it < 2; ++it) {
            int r = lr + it * 64;
            int c = k0 + lc;
            int o = o0 + r;
            uint4 vh = {0, 0, 0, 0}, vl = {0, 0, 0, 0};
            if (o < O && c < CPW) {
                size_t goff = (size_t)o * CPW + c;
                vh = *(const uint4*)(Bh + goff);
                vl = *(const uint4*)(Bl + goff);
            }
            *(uint4*)&sBh[r * PITCH + lc] = vh;
            *(uint4*)&sBl[r * PITCH + lc] = vl;
        }
        __syncthreads();
        s16x8 ah[4], al[4], bh[4], bl[4];
#pragma unroll
        for (int mt = 0; mt < 4; ++mt) {
            int rowoff = (wm + mt * 16 + col15) * PITCH + quad * 8;
            ah[mt] = *(const s16x8*)&sAh[rowoff];
            al[mt] = *(const s16x8*)&sAl[rowoff];
        }
#pragma unroll
        for (int ot = 0; ot < 4; ++ot) {
            int rowoff = (wo + ot * 16 + col15) * PITCH + quad * 8;
            bh[ot] = *(const s16x8*)&sBh[rowoff];
            bl[ot] = *(const s16x8*)&sBl[rowoff];
        }
#pragma unroll
        for (int mt = 0; mt < 4; ++mt)
#pragma unroll
            for (int ot = 0; ot < 4; ++ot) {
                acc[mt][ot] = __builtin_amdgcn_mfma_f32_16x16x32_bf16(
                    ah[mt], bl[ot], acc[mt][ot], 0, 0, 0);
                acc[mt][ot] = __builtin_amdgcn_mfma_f32_16x16x32_bf16(
                    al[mt], bh[ot], acc[mt][ot], 0, 0, 0);
                acc[mt][ot] = __builtin_amdgcn_mfma_f32_16x16x32_bf16(
                    ah[mt], bh[ot], acc[mt][ot], 0, 0, 0);
            }
        __syncthreads();
    }
    if (redK == 0) {
#pragma unroll
        for (int mt = 0; mt < 4; ++mt)
#pragma unroll
            for (int ot = 0; ot < 4; ++ot) {
                int og = o0 + wo + ot * 16 + col15;
                if (og < O) {
#pragma unroll
                    for (int r = 0; r < 4; ++r) {
                        int mg = m0 + wm + mt * 16 + quad * 4 + r;
                        Y[(size_t)mg * O + og] = acc[mt][ot][r];
                    }
                }
            }
    } else if (redK == 32) {
        // 4 centers / 128-row tile; center-local = (wm>>5) + (mt>>1).
#pragma unroll
        for (int ot = 0; ot < 4; ++ot) {
            int og = o0 + wo + ot * 16 + col15;
#pragma unroll
            for (int cp = 0; cp < 2; ++cp) {
                float mx = acc[2 * cp][ot][0];
                float mn = mx;
#pragma unroll
                for (int mi = 0; mi < 2; ++mi)
#pragma unroll
                    for (int r = 0; r < 4; ++r) {
                        float v = acc[2 * cp + mi][ot][r];
                        mx = fmaxf(mx, v);
                        mn = fminf(mn, v);
                    }
                mx = fmaxf(mx, __shfl_xor(mx, 16));
                mx = fmaxf(mx, __shfl_xor(mx, 32));
                mn = fminf(mn, __shfl_xor(mn, 16));
                mn = fminf(mn, __shfl_xor(mn, 32));
                if (quad == 0) {
                    int ctr = (m0 >> 5) + (wm >> 5) + cp;
                    Vmax[(size_t)ctr * O + og] = mx;
                    Vmin[(size_t)ctr * O + og] = mn;
                }
            }
        }
    } else {   // redK == 64: 2 centers / tile; center-local = wm>>6.
#pragma unroll
        for (int ot = 0; ot < 4; ++ot) {
            int og = o0 + wo + ot * 16 + col15;
            float mx = acc[0][ot][0];
            float mn = mx;
#pragma unroll
            for (int mt = 0; mt < 4; ++mt)
#pragma unroll
                for (int r = 0; r < 4; ++r) {
                    float v = acc[mt][ot][r];
                    mx = fmaxf(mx, v);
                    mn = fminf(mn, v);
                }
            mx = fmaxf(mx, __shfl_xor(mx, 16));
            mx = fmaxf(mx, __shfl_xor(mx, 32));
            mn = fminf(mn, __shfl_xor(mn, 16));
            mn = fminf(mn, __shfl_xor(mn, 32));
            if (quad == 0) {
                int ctr = (m0 >> 6) + (wm >> 6);
                Vmax[(size_t)ctr * O + og] = mx;
                Vmin[(size_t)ctr * O + og] = mn;
            }
        }
    }
    // BN stats epilogue (R13-identical fixed-order block combine), then two
    // f64 atomicAdds per channel (simple tail — no register-pressure bomb).
#pragma unroll
    for (int ot = 0; ot < 4; ++ot) {
        float s = 0.f, s2 = 0.f;
#pragma unroll
        for (int mt = 0; mt < 4; ++mt)
#pragma unroll
            for (int r = 0; r < 4; ++r) {
                float v = acc[mt][ot][r];
                s += v;
                s2 += v * v;
            }
        int slot = ((wid * 4 + quad) * 16 + col15) * 4 + ot;
        sred[slot * 2] = s;
        sred[slot * 2 + 1] = s2;
    }
    __syncthreads();
    if (tid < 128) {
        int col = tid;
        int o = o0 + col;
        if (o < O) {
            int cb = col >> 6;
            int ot = (col & 63) >> 4;
            int c15 = col & 15;
            double S = 0.0, S2 = 0.0;
#pragma unroll
            for (int wp = 0; wp < 2; ++wp) {
                int wd = cb + wp * 2;
#pragma unroll
                for (int q = 0; q < 4; ++q) {
                    int slot = ((wd * 4 + q) * 16 + c15) * 4 + ot;
                    S += (double)sred[slot * 2];
                    S2 += (double)sred[slot * 2 + 1];
                }
            }
            atomicAdd(&pSout[o], S);
            atomicAdd(&pQout[o], S2);
        }
    }
}

// ---------------- BN + ReLU + max over K (+ optional SA2 query_ball) -------
// vmode 0: loop K rows of Y. vmode 1: read Vmax/Vmin (Y=Vmax) — monotone
// selection: v = sc>=0 ? vmax : vmin; out = relu(v*sc+sh). Exact.
__global__ __launch_bounds__(256) void bn_relu_max(
    const float* __restrict__ Y, const float* __restrict__ Vmin,
    const double* __restrict__ pS, const double* __restrict__ pQ,
    const float* __restrict__ gv, const float* __restrict__ bv, double invM,
    float* __restrict__ out, int Stot, int K, int O, int vmode, int nMain,
    const float* __restrict__ qbXyz, const float* __restrict__ qbCtr,
    int* __restrict__ qbOut)
{
    if ((int)blockIdx.x >= nMain) {   // piggyback: SA2 query_ball (4 waves)
        int wid = threadIdx.x >> 6, lane = threadIdx.x & 63;
        int gw = ((int)blockIdx.x - nMain) * 4 + wid;
        if (gw < 1024) qb2_dev(qbXyz, qbCtr, qbOut, gw, lane);
        return;
    }
    int idx = blockIdx.x * 256 + threadIdx.x;
    if (idx >= Stot * O) return;
    int s = idx / O;
    int o = idx - s * O;
    double S = pS[o], Q = pQ[o];
    double mean = S * invM;
    double var = Q * invM - mean * mean;
    float varf = (float)var;
    if (varf < 0.f) varf = 0.f;
    float sc = gv[o] * rsqrtf(varf + 1e-5f);
    float sh = bv[o] - (float)mean * sc;
    if (vmode) {
        float vmax = Y[(size_t)s * O + o];
        float vmin = Vmin[(size_t)s * O + o];
        float v = (sc >= 0.f) ? vmax : vmin;
        out[idx] = fmaxf(v * sc + sh, 0.f);
        return;
    }
    const float* basep = Y + (size_t)s * K * O + o;
    float mx = 0.f;
    for (int k = 0; k < K; ++k) {
        float v = basep[(size_t)k * O] * sc + sh;
        v = fmaxf(v, 0.f);
        mx = fmaxf(mx, v);
    }
    out[idx] = mx;
}

// ============================================================================
extern "C" void kernel_launch(void* const* d_in, const int* in_sizes, int n_in,
                              void* d_out, int out_size, void* d_ws, size_t ws_size,
                              hipStream_t stream)
{
    const float* xin = (const float*)d_in[0];
    const float* w[9]; const float* g[9]; const float* bb[9];
    for (int i = 0; i < 9; ++i) {
        w[i]  = (const float*)d_in[1 + 3 * i];
        g[i]  = (const float*)d_in[2 + 3 * i];
        bb[i] = (const float*)d_in[3 + 3 * i];
    }

    char* base = (char*)d_ws;
    size_t off = 0;
    auto alloc = [&](size_t bytes) -> void* {
        void* p = base + off;
        off = (off + bytes + 255) & ~(size_t)255;
        return p;
    };
    const int OC[9][3] = {{64,4,8},{64,64,64},{128,64,64},
                          {128,131,136},{128,128,128},{256,128,128},
                          {256,259,264},{512,256,256},{1024,512,512}};
    size_t woff[10]; woff[0] = 0;
    for (int i = 0; i < 9; ++i) woff[i + 1] = woff[i] + (size_t)OC[i][0] * OC[i][2];

    // --- small / metadata region (memset-protected) ---
    int*    fps1   = (int*)alloc((size_t)4096 * 4);
    int*    fps2   = (int*)alloc((size_t)1024 * 4);
    int*    qb2    = (int*)alloc((size_t)65536 * 4);
    float*  nx1    = (float*)alloc((size_t)12288 * 4);
    float*  nx2    = (float*)alloc((size_t)3072 * 4);
    float*  feat1  = (float*)alloc((size_t)524288 * 4);
    float*  feat2  = (float*)alloc((size_t)262144 * 4);
    double* partS  = (double*)alloc((size_t)9 * 1024 * 8);   // per-layer sums
    double* partQ  = (double*)alloc((size_t)9 * 1024 * 8);   // per-layer sumsq
    unsigned short* WH = (unsigned short*)alloc(woff[9] * 2);
    unsigned short* WL = (unsigned short*)alloc(woff[9] * 2);
    const size_t zeroBytes = off;
    // --- big ping/pong buffers (fully written before read at every use) ---
    float*  XG = (float*)alloc((size_t)65536 * 136 * 4);
    float*  A  = (float*)alloc((size_t)16777216 * 4);
    if (off > ws_size) return;

    // Defensive zero of the metadata region only (~7 MB): indices and the
    // per-layer stat accumulators start at 0 every invocation.
    hipMemsetAsync(d_ws, 0, zeroBytes, stream);

    PWArgs pwa;
    for (int i = 0; i < 9; ++i) {
        pwa.w[i] = w[i]; pwa.off[i] = (unsigned)woff[i];
        pwa.O[i] = OC[i][0]; pwa.C[i] = OC[i][1]; pwa.CP[i] = OC[i][2];
    }
    const int nPrep = (int)((woff[9] + 255) / 256);

    auto gemm = [&](const float* X, int prevLi, double invMprev, int li,
                    float* Y, int YB, int OB, int AC, int CPW, int O,
                    int gmode, const int* gqb, const float* gxyz,
                    const float* gctr, const float* gfeat,
                    int redK, float* Vmax, float* Vmin) {
        gemm_fused<<<dim3(YB, OB), 256, 0, stream>>>(
            X,
            prevLi >= 0 ? partS + (size_t)prevLi * 1024 : nullptr,
            prevLi >= 0 ? partQ + (size_t)prevLi * 1024 : nullptr,
            prevLi >= 0 ? g[prevLi] : nullptr,
            prevLi >= 0 ? bb[prevLi] : nullptr,
            invMprev, prevLi >= 0 ? 1 : 0,
            WH + woff[li], WL + woff[li], Y,
            partS + (size_t)li * 1024, partQ + (size_t)li * 1024,
            AC, CPW, O, gmode, gqb, gxyz, gctr, gfeat, redK, Vmax, Vmin);
    };

    const double inv1 = 1.0 / 131072.0;
    const double inv2 = 1.0 / 65536.0;
    const double inv3 = 1.0 / 1024.0;

    // ---------------- SA1 ----------------
    fps_block<256, 16, 4><<<8 + nPrep, 256, 0, stream>>>(
        xin, 512, fps1, nx1, 8, pwa, WH, WL, (int)woff[9]);
    // qb_group1 (group + L1_0 fused): blocks 0-1023 -> Y(=A) + layer-0 stats;
    // blocks 1024-1031: SA2 single-wave FPS piggyback.
    qb_group1<<<1024 + 8, 256, 0, stream>>>(
        xin, nx1, w[0], A, partS + 0, partQ + 0, 1024, nx1, fps2, nx2);

    gemm(A, 0, inv1, 1, XG, 1024, 1, 64, 64, 64, 0, nullptr, nullptr, nullptr, nullptr, 0, nullptr, nullptr);
    // L1_2: K=32 reduce mode — Vmax/Vmin (4096x128) into A, no Y write.
    gemm(XG, 1, inv1, 2, A, 1024, 1, 64, 64, 128, 0, nullptr, nullptr, nullptr, nullptr, 32, A, A + 524288);
    // bn_relu_max vmode=1 (2048 blocks) + SA2 query_ball (256 blocks) fused.
    bn_relu_max<<<2048 + 256, 256, 0, stream>>>(
        A, A + 524288, partS + 2 * 1024, partQ + 2 * 1024, g[2], bb[2], inv1,
        feat1, 4096, 32, 128, 1, 2048, nx1, nx2, qb2);

    // ---------------- SA2 ----------------
    // L2_0: A-staging gathers group2 inline (qb2/nx1/feat1) — no XG pass.
    gemm(nullptr, -1, 0.0, 3, XG, 512, 1, 136, 136, 128, 2, qb2, nx1, nx2, feat1, 0, nullptr, nullptr);
    gemm(XG, 3, inv2, 4, A, 512, 1, 128, 128, 128, 0, nullptr, nullptr, nullptr, nullptr, 0, nullptr, nullptr);
    // L2_2: K=64 reduce mode — Vmax/Vmin (1024x256) into XG, no Y write.
    gemm(A, 4, inv2, 5, XG, 512, 2, 128, 128, 256, 0, nullptr, nullptr, nullptr, nullptr, 64, XG, XG + 262144);
    bn_relu_max<<<(1024 * 256) / 256, 256, 0, stream>>>(
        XG, XG + 262144, partS + 5 * 1024, partQ + 5 * 1024, g[5], bb[5], inv2,
        feat2, 1024, 64, 256, 1, 1024 * 256 / 256, nullptr, nullptr, nullptr);

    // ---------------- SA3 (group_all) ----------------
    // L3_0: A-staging gathers group3 inline (nx2/feat2) — no XG pass.
    gemm(nullptr, -1, 0.0, 6, A, 8, 2, 264, 264, 256, 3, nullptr, nullptr, nx2, feat2, 0, nullptr, nullptr);
    gemm(A, 6, inv3, 7, XG, 8, 4, 256, 256, 512, 0, nullptr, nullptr, nullptr, nullptr, 0, nullptr, nullptr);
    gemm(XG, 7, inv3, 8, A, 8, 8, 512, 512, 1024, 0, nullptr, nullptr, nullptr, nullptr, 0, nullptr, nullptr);
    bn_relu_max<<<(8 * 1024) / 256, 256, 0, stream>>>(
        A, nullptr, partS + 8 * 1024, partQ + 8 * 1024, g[8], bb[8], inv3,
        (float*)d_out, 8, 128, 1024, 0, (8 * 1024) / 256,
        nullptr, nullptr, nullptr);
}